// Round 1
// baseline (2315.627 us; speedup 1.0000x reference)
//
#include <hip/hip_runtime.h>
#include <math.h>

#define Hh 256
#define Dd 64
#define Nn 32
#define YS 36   // padded stride for 256x32 LDS tiles (16B-aligned rows, conflict-spread)

__global__ __launch_bounds__(256, 1) void lnn_kernel(
    const float* __restrict__ x,
    const float* __restrict__ mW1, const float* __restrict__ mb1,
    const float* __restrict__ mW2, const float* __restrict__ mb2,
    const float* __restrict__ mW3,
    const float* __restrict__ qW1, const float* __restrict__ qb1,
    const float* __restrict__ qW2, const float* __restrict__ qb2,
    const float* __restrict__ qW3,
    float* __restrict__ out)
{
  const int s = blockIdx.x;
  const int t = threadIdx.x;

  __shared__ float xr[Dd];
  __shared__ float act1[Hh];   // act'(z1)
  __shared__ float d2a[Hh];    // act''(z1)
  __shared__ float h1[Hh];     // act(z1)
  __shared__ float s2[Hh];     // w3_j * act'(z2_j)
  __shared__ float bco[Hh];    // w3_j * act''(z2_j)
  __shared__ float uarr[Hh];   // act1*v  (later: act1*r)
  __shared__ float aarr[Hh];   // d2a*v
  __shared__ float rbuf[Hh];   // r_k = W1_top^T qdot
  __shared__ float twv[Hh];    // b_j * t_j
  __shared__ float Y[Hh * YS]; // Y[k][p] = W1bot[p,k]*act1[k]; later W1bot[p,k]
  __shared__ float Tl[Hh * YS];// T[j][p] (j-major)
  __shared__ float red[256];
  __shared__ float jacv[Nn];
  __shared__ float Bqv[Nn];
  __shared__ float Aug[Nn][Nn + 2]; // [A | rhs], stride 34
  __shared__ float fvec[Nn];
  __shared__ int piv;

  if (t < Dd) xr[t] = x[s * Dd + t];
  if (t < Nn) { jacv[t] = 0.f; Bqv[t] = 0.f; }
  __syncthreads();

  float Apart[4] = {0.f, 0.f, 0.f, 0.f};
  const int pA = t >> 3;        // 0..31
  const int qA = (t & 7) * 4;   // 0,4,...,28

  for (int net = 0; net < 2; ++net) {
    const float* W1 = net ? qW1 : mW1;
    const float* b1 = net ? qb1 : mb1;
    const float* W2 = net ? qW2 : mW2;
    const float* b2 = net ? qb2 : mb2;
    const float* W3 = net ? qW3 : mW3;

    // ---- layer 1: z1_t, activation + derivatives ----
    {
      float z = b1[t];
      for (int i = 0; i < Dd; ++i) z = fmaf(xr[i], W1[i * Hh + t], z);
      float f0, f1, f2;
      if (net == 0) {
        float sg = 1.f / (1.f + expf(-z));
        f0 = (z > 20.f) ? z : log1pf(expf(z));
        f1 = sg;
        f2 = sg * (1.f - sg);
      } else {
        float th = tanhf(0.5f * z);
        float sech2 = 1.f - th * th;
        f0 = z * th;
        f1 = th + 0.5f * z * sech2;
        f2 = sech2 * (1.f - 0.5f * z * th);
      }
      h1[t] = f0; act1[t] = f1; d2a[t] = f2;
    }
    __syncthreads();

    // ---- layer 2: z2_t, s2, bco ----
    {
      float z2 = b2[t];
      for (int k = 0; k < Hh; ++k) z2 = fmaf(h1[k], W2[k * Hh + t], z2);
      float w3t = W3[t];
      float g1, g2v;
      if (net == 0) {
        float sg = 1.f / (1.f + expf(-z2));
        g1 = sg; g2v = sg * (1.f - sg);
      } else {
        float th = tanhf(0.5f * z2);
        float sech2 = 1.f - th * th;
        g1 = th + 0.5f * z2 * sech2;
        g2v = sech2 * (1.f - 0.5f * z2 * th);
      }
      s2[t] = w3t * g1; bco[t] = w3t * g2v;
    }
    __syncthreads();

    // ---- v_k = (W2 s2)_k ; u=act1*v ; a=d2a*v ; r_k = W1_top^T qdot ----
    {
      float acc = 0.f;
      const float* wr = W2 + t * Hh;
      for (int j = 0; j < Hh; j += 4) {
        float4 w = *(const float4*)(wr + j);
        acc = fmaf(w.x, s2[j], acc);
        acc = fmaf(w.y, s2[j + 1], acc);
        acc = fmaf(w.z, s2[j + 2], acc);
        acc = fmaf(w.w, s2[j + 3], acc);
      }
      uarr[t] = act1[t] * acc;
      aarr[t] = d2a[t] * acc;
    }
    {
      float acc = 0.f;
      for (int i = 0; i < Nn; ++i) acc = fmaf(xr[Nn + i], W1[i * Hh + t], acc);
      rbuf[t] = acc;
    }
    __syncthreads();

    // ---- jac[:32] partial: grad_i = sum_k W1[i,k] u_k ----
    {
      int i = t & 31, seg = t >> 5;
      float acc = 0.f;
      const float* wr = W1 + i * Hh + seg * 32;
      for (int k = 0; k < 32; ++k) acc = fmaf(wr[k], uarr[seg * 32 + k], acc);
      red[t] = acc;
    }
    __syncthreads();
    if (t < Nn) {
      float acc = 0.f;
      for (int g = 0; g < 8; ++g) acc += red[g * 32 + t];
      jacv[t] += acc;
    }
    __syncthreads();

    // ---- Bq term1: sum_k W1bot[p,k] * a_k * r_k ----
    {
      int p = t & 31, seg = t >> 5;
      float acc = 0.f;
      const float* wr = W1 + (Nn + p) * Hh + seg * 32;
      for (int k = 0; k < 32; ++k) {
        int kk = seg * 32 + k;
        acc = fmaf(wr[k], aarr[kk] * rbuf[kk], acc);
      }
      red[t] = acc;
    }
    __syncthreads();
    if (t < Nn) {
      float acc = 0.f;
      for (int g = 0; g < 8; ++g) acc += red[g * 32 + t];
      Bqv[t] += acc;
    }
    __syncthreads();
    uarr[t] = act1[t] * rbuf[t];   // repurpose: act1 ⊙ r
    __syncthreads();

    // ---- t_j = sum_k W2[k,j]*(act1 r)_k ; twv = bco * t ;  Y fill ----
    {
      float acc = 0.f;
      for (int k = 0; k < Hh; ++k) acc = fmaf(W2[k * Hh + t], uarr[k], acc);
      twv[t] = bco[t] * acc;
    }
    {
      float a = act1[t];
      #pragma unroll
      for (int i = 0; i < Nn; i += 4) {
        float4 w;
        w.x = W1[(Nn + i    ) * Hh + t] * a;
        w.y = W1[(Nn + i + 1) * Hh + t] * a;
        w.z = W1[(Nn + i + 2) * Hh + t] * a;
        w.w = W1[(Nn + i + 3) * Hh + t] * a;
        *(float4*)&Y[t * YS + i] = w;
      }
    }
    __syncthreads();

    // ---- T-loop: T[p][j] = sum_k Y[k][p] * W2[k][j]  (8p x 4j per thread) ----
    {
      const int p0 = (t >> 6) * 8;      // per-wave p-group (broadcast LDS reads)
      const int j0 = (t & 63) * 4;      // coalesced float4 W2 reads
      float acc[8][4];
      #pragma unroll
      for (int a = 0; a < 8; ++a)
        #pragma unroll
        for (int b = 0; b < 4; ++b) acc[a][b] = 0.f;
      for (int k = 0; k < Hh; ++k) {
        float4 wv = *(const float4*)(W2 + k * Hh + j0);
        float4 y0 = *(const float4*)&Y[k * YS + p0];
        float4 y1 = *(const float4*)&Y[k * YS + p0 + 4];
        float yv[8] = {y0.x, y0.y, y0.z, y0.w, y1.x, y1.y, y1.z, y1.w};
        float wvv[4] = {wv.x, wv.y, wv.z, wv.w};
        #pragma unroll
        for (int a = 0; a < 8; ++a)
          #pragma unroll
          for (int b = 0; b < 4; ++b)
            acc[a][b] = fmaf(yv[a], wvv[b], acc[a][b]);
      }
      #pragma unroll
      for (int b = 0; b < 4; ++b) {
        *(float4*)&Tl[(j0 + b) * YS + p0]     = make_float4(acc[0][b], acc[1][b], acc[2][b], acc[3][b]);
        *(float4*)&Tl[(j0 + b) * YS + p0 + 4] = make_float4(acc[4][b], acc[5][b], acc[6][b], acc[7][b]);
      }
    }
    __syncthreads();

    // ---- overwrite Y with plain W1bot^T (for A's W-term) ----
    {
      #pragma unroll
      for (int i = 0; i < Nn; i += 4) {
        float4 w;
        w.x = W1[(Nn + i    ) * Hh + t];
        w.y = W1[(Nn + i + 1) * Hh + t];
        w.z = W1[(Nn + i + 2) * Hh + t];
        w.w = W1[(Nn + i + 3) * Hh + t];
        *(float4*)&Y[t * YS + i] = w;
      }
    }

    // ---- Bq term2: sum_j T[p][j] * twv[j] ----
    {
      int p = t & 31, seg = t >> 5;
      float acc = 0.f;
      for (int j = 0; j < 32; ++j) {
        int jj = seg * 32 + j;
        acc = fmaf(Tl[jj * YS + p], twv[jj], acc);
      }
      red[t] = acc;
    }
    __syncthreads();
    if (t < Nn) {
      float acc = 0.f;
      for (int g = 0; g < 8; ++g) acc += red[g * 32 + t];
      Bqv[t] += acc;
    }
    __syncthreads();

    // ---- A accumulation: sum_j b_j T[p,j]T[q,j] + sum_k a_k W[p,k]W[q,k] ----
    {
      float a0 = 0.f, a1 = 0.f, a2 = 0.f, a3 = 0.f;
      for (int j = 0; j < Hh; ++j) {
        float c = bco[j] * Tl[j * YS + pA];
        float4 tq = *(const float4*)&Tl[j * YS + qA];
        a0 = fmaf(c, tq.x, a0);
        a1 = fmaf(c, tq.y, a1);
        a2 = fmaf(c, tq.z, a2);
        a3 = fmaf(c, tq.w, a3);
      }
      for (int k = 0; k < Hh; ++k) {
        float c = aarr[k] * Y[k * YS + pA];
        float4 wq = *(const float4*)&Y[k * YS + qA];
        a0 = fmaf(c, wq.x, a0);
        a1 = fmaf(c, wq.y, a1);
        a2 = fmaf(c, wq.z, a2);
        a3 = fmaf(c, wq.w, a3);
      }
      Apart[0] += a0; Apart[1] += a1; Apart[2] += a2; Apart[3] += a3;
    }
    __syncthreads();   // before next net reuses all buffers
  }

  // ---- finalize A (+2I) and rhs ----
  Aug[pA][qA + 0] = Apart[0];
  Aug[pA][qA + 1] = Apart[1];
  Aug[pA][qA + 2] = Apart[2];
  Aug[pA][qA + 3] = Apart[3];
  __syncthreads();
  if (t < Nn) {
    Aug[t][t] += 2.0f;
    Aug[t][Nn] = jacv[t] - Bqv[t];
  }
  __syncthreads();

  // ---- Gauss-Jordan with partial pivoting on [A | rhs] ----
  for (int step = 0; step < Nn; ++step) {
    if (t == 0) {
      int pr = step; float pm = fabsf(Aug[step][step]);
      for (int r = step + 1; r < Nn; ++r) {
        float v = fabsf(Aug[r][step]);
        if (v > pm) { pm = v; pr = r; }
      }
      piv = pr;
    }
    __syncthreads();
    {
      int pv = piv;
      if (pv != step && t <= Nn) {
        float tmp = Aug[step][t]; Aug[step][t] = Aug[pv][t]; Aug[pv][t] = tmp;
      }
    }
    __syncthreads();
    if (t < Nn) fvec[t] = (t == step) ? 0.f : Aug[t][step] / Aug[step][step];
    __syncthreads();
    for (int idx = t; idx < Nn * (Nn + 1); idx += 256) {
      int r = idx / (Nn + 1), c = idx % (Nn + 1);
      if (r != step) Aug[r][c] -= fvec[r] * Aug[step][c];
    }
    __syncthreads();
  }

  if (t < Nn) {
    out[s * Dd + t] = xr[Nn + t];                       // qdot
    out[s * Dd + Nn + t] = Aug[t][Nn] / Aug[t][t];      // qdd
  }
}

extern "C" void kernel_launch(void* const* d_in, const int* in_sizes, int n_in,
                              void* d_out, int out_size, void* d_ws, size_t ws_size,
                              hipStream_t stream) {
  const float* x   = (const float*)d_in[0];
  const float* mW1 = (const float*)d_in[1];
  const float* mb1 = (const float*)d_in[2];
  const float* mW2 = (const float*)d_in[3];
  const float* mb2 = (const float*)d_in[4];
  const float* mW3 = (const float*)d_in[5];
  const float* qW1 = (const float*)d_in[6];
  const float* qb1 = (const float*)d_in[7];
  const float* qW2 = (const float*)d_in[8];
  const float* qb2 = (const float*)d_in[9];
  const float* qW3 = (const float*)d_in[10];

  const int B = in_sizes[0] / Dd;   // 4096
  lnn_kernel<<<dim3(B), dim3(256), 0, stream>>>(
      x, mW1, mb1, mW2, mb2, mW3, qW1, qb1, qW2, qb2, qW3, (float*)d_out);
}

// Round 2
// 986.363 us; speedup vs baseline: 2.3476x; 2.3476x over previous
//
#include <hip/hip_runtime.h>
#include <math.h>

#define Hh 256
#define Dd 64
#define Nn 32
#define US 36   // U tile stride (16B-aligned rows for float4)
#define AS 35   // Aug stride (odd*... -> (3r+c)%32 conflict-free elimination)

__global__ __launch_bounds__(256, 3) void lnn_kernel(
    const float* __restrict__ x,
    const float* __restrict__ mW1, const float* __restrict__ mb1,
    const float* __restrict__ mW2, const float* __restrict__ mb2,
    const float* __restrict__ mW3,
    const float* __restrict__ qW1, const float* __restrict__ qb1,
    const float* __restrict__ qW2, const float* __restrict__ qb2,
    const float* __restrict__ qW3,
    float* __restrict__ out)
{
  const int s = blockIdx.x;
  const int t = threadIdx.x;

  // Single 36KB tile buffer, time-multiplexed:
  //   P3-P5: U[k][p] = W1bot[p,k] (plain), then scaled in-place by act1[k]
  //   P7-P8: Tl[j][p] = T[p][j]
  __shared__ float U[Hh * US];
  __shared__ float xr[Dd];
  __shared__ float act1[Hh], d2a[Hh], s2[Hh], bco[Hh], uarr[Hh], aarr[Hh], rbuf[Hh];
  __shared__ float bufA[Hh];   // h1 (P1-P2) / jac-part (P4-P5) / Bq2-part (P8-P9)
  __shared__ float bufB[Hh];   // Bq1-part (P4-P5) / twv (P6-P8)
  __shared__ float jacv[Nn], Bqv[Nn];
  __shared__ float Aug[Nn][AS];

  if (t < Dd) xr[t] = x[s * Dd + t];
  if (t < Nn) { jacv[t] = 0.f; Bqv[t] = 0.f; }
  __syncthreads();

  float Apart[4] = {0.f, 0.f, 0.f, 0.f};
  const int pA = t >> 3;        // 0..31
  const int qA = (t & 7) * 4;   // 0,4,...,28

  for (int net = 0; net < 2; ++net) {
    const float* W1 = net ? qW1 : mW1;
    const float* b1 = net ? qb1 : mb1;
    const float* W2 = net ? qW2 : mW2;
    const float* b2 = net ? qb2 : mb2;
    const float* W3 = net ? qW3 : mW3;

    // ---- P1: z1, activation + derivatives ----
    {
      float z = b1[t];
      #pragma unroll 8
      for (int i = 0; i < Dd; ++i) z = fmaf(xr[i], W1[i * Hh + t], z);
      float f0, f1, f2;
      if (net == 0) {
        float e = __expf(-z);
        float sg = 1.f / (1.f + e);
        f0 = (z > 20.f) ? z : __logf(1.f + __expf(z));
        f1 = sg; f2 = sg * (1.f - sg);
      } else {
        float az = fabsf(z);
        float e = __expf(-az);
        float th = (1.f - e) / (1.f + e);
        th = (z < 0.f) ? -th : th;
        float sech2 = 1.f - th * th;
        f0 = z * th;
        f1 = th + 0.5f * z * sech2;
        f2 = sech2 * (1.f - 0.5f * z * th);
      }
      bufA[t] = f0; act1[t] = f1; d2a[t] = f2;
    }
    __syncthreads();

    // ---- P2: z2 -> s2, bco ; rbuf ----
    {
      float z2 = b2[t];
      for (int k = 0; k < Hh; k += 4) {
        float4 h = *(const float4*)&bufA[k];
        z2 = fmaf(h.x, W2[(k    ) * Hh + t], z2);
        z2 = fmaf(h.y, W2[(k + 1) * Hh + t], z2);
        z2 = fmaf(h.z, W2[(k + 2) * Hh + t], z2);
        z2 = fmaf(h.w, W2[(k + 3) * Hh + t], z2);
      }
      float w3t = W3[t];
      float g1, g2v;
      if (net == 0) {
        float e = __expf(-z2);
        float sg = 1.f / (1.f + e);
        g1 = sg; g2v = sg * (1.f - sg);
      } else {
        float az = fabsf(z2);
        float e = __expf(-az);
        float th = (1.f - e) / (1.f + e);
        th = (z2 < 0.f) ? -th : th;
        float sech2 = 1.f - th * th;
        g1 = th + 0.5f * z2 * sech2;
        g2v = sech2 * (1.f - 0.5f * z2 * th);
      }
      s2[t] = w3t * g1; bco[t] = w3t * g2v;
      float racc = 0.f;
      #pragma unroll 8
      for (int i = 0; i < Nn; ++i) racc = fmaf(xr[Nn + i], W1[i * Hh + t], racc);
      rbuf[t] = racc;
    }
    __syncthreads();

    // ---- P3: v -> uarr, aarr ; fill U = plain W1bot^T (k-major) ----
    {
      float acc = 0.f;
      const float* wr = W2 + t * Hh;
      for (int j = 0; j < Hh; j += 4) {
        float4 w = *(const float4*)(wr + j);
        float4 sv = *(const float4*)&s2[j];
        acc = fmaf(w.x, sv.x, acc);
        acc = fmaf(w.y, sv.y, acc);
        acc = fmaf(w.z, sv.z, acc);
        acc = fmaf(w.w, sv.w, acc);
      }
      uarr[t] = act1[t] * acc;
      aarr[t] = d2a[t] * acc;
      #pragma unroll
      for (int i = 0; i < Nn; i += 4) {
        float4 w;
        w.x = W1[(Nn + i    ) * Hh + t];
        w.y = W1[(Nn + i + 1) * Hh + t];
        w.z = W1[(Nn + i + 2) * Hh + t];
        w.w = W1[(Nn + i + 3) * Hh + t];
        *(float4*)&U[t * US + i] = w;
      }
    }
    __syncthreads();

    // ---- P4: jac partial + Bq1 partial + A W-term (all read-only) ----
    {
      int i = t & 31, seg = t >> 5;
      float ja = 0.f, bq = 0.f;
      const float* wr = W1 + i * Hh + seg * 32;
      #pragma unroll 4
      for (int k = 0; k < 32; ++k) {
        int kk = seg * 32 + k;
        ja = fmaf(wr[k], uarr[kk], ja);
        bq = fmaf(U[kk * US + i], aarr[kk] * rbuf[kk], bq);
      }
      bufA[t] = ja; bufB[t] = bq;
    }
    {
      float a0 = 0.f, a1 = 0.f, a2 = 0.f, a3 = 0.f;
      for (int k = 0; k < Hh; ++k) {
        float c = aarr[k] * U[k * US + pA];
        float4 wq = *(const float4*)&U[k * US + qA];
        a0 = fmaf(c, wq.x, a0);
        a1 = fmaf(c, wq.y, a1);
        a2 = fmaf(c, wq.z, a2);
        a3 = fmaf(c, wq.w, a3);
      }
      Apart[0] += a0; Apart[1] += a1; Apart[2] += a2; Apart[3] += a3;
    }
    __syncthreads();

    // ---- P5: reduce jac/Bq1 ; scale U in place by act1 ; uarr = act1*rbuf ----
    if (t < Nn) {
      float ja = 0.f, bq = 0.f;
      #pragma unroll
      for (int g = 0; g < 8; ++g) { ja += bufA[g * 32 + t]; bq += bufB[g * 32 + t]; }
      jacv[t] += ja; Bqv[t] += bq;
    }
    {
      float a = act1[t];
      #pragma unroll
      for (int i = 0; i < Nn; i += 4) {
        float4 w = *(float4*)&U[t * US + i];
        w.x *= a; w.y *= a; w.z *= a; w.w *= a;
        *(float4*)&U[t * US + i] = w;
      }
      uarr[t] = a * rbuf[t];
    }
    __syncthreads();

    // ---- P6: twv ; T-loop into registers ----
    {
      float tacc = 0.f;
      for (int k = 0; k < Hh; k += 4) {
        float4 uv = *(const float4*)&uarr[k];
        tacc = fmaf(uv.x, W2[(k    ) * Hh + t], tacc);
        tacc = fmaf(uv.y, W2[(k + 1) * Hh + t], tacc);
        tacc = fmaf(uv.z, W2[(k + 2) * Hh + t], tacc);
        tacc = fmaf(uv.w, W2[(k + 3) * Hh + t], tacc);
      }
      bufB[t] = bco[t] * tacc;
    }
    float acc[8][4];
    {
      const int p0 = (t >> 6) * 8;   // per-wave p-group -> broadcast LDS reads
      const int j0 = (t & 63) * 4;   // coalesced float4 W2 reads
      #pragma unroll
      for (int a = 0; a < 8; ++a)
        #pragma unroll
        for (int b = 0; b < 4; ++b) acc[a][b] = 0.f;
      for (int k = 0; k < Hh; ++k) {
        float4 wv = *(const float4*)(W2 + k * Hh + j0);
        float4 y0 = *(const float4*)&U[k * US + p0];
        float4 y1 = *(const float4*)&U[k * US + p0 + 4];
        float yv[8] = {y0.x, y0.y, y0.z, y0.w, y1.x, y1.y, y1.z, y1.w};
        float wvv[4] = {wv.x, wv.y, wv.z, wv.w};
        #pragma unroll
        for (int a = 0; a < 8; ++a)
          #pragma unroll
          for (int b = 0; b < 4; ++b)
            acc[a][b] = fmaf(yv[a], wvv[b], acc[a][b]);
      }
    }
    __syncthreads();

    // ---- P7: write T into U buffer as Tl[j][p] ----
    {
      const int p0 = (t >> 6) * 8;
      const int j0 = (t & 63) * 4;
      #pragma unroll
      for (int b = 0; b < 4; ++b) {
        *(float4*)&U[(j0 + b) * US + p0]     = make_float4(acc[0][b], acc[1][b], acc[2][b], acc[3][b]);
        *(float4*)&U[(j0 + b) * US + p0 + 4] = make_float4(acc[4][b], acc[5][b], acc[6][b], acc[7][b]);
      }
    }
    __syncthreads();

    // ---- P8: Bq2 partial + A T-term ----
    {
      int p = t & 31, seg = t >> 5;
      float acc2 = 0.f;
      #pragma unroll 4
      for (int j = 0; j < 32; ++j) {
        int jj = seg * 32 + j;
        acc2 = fmaf(U[jj * US + p], bufB[jj], acc2);
      }
      bufA[t] = acc2;
    }
    {
      float a0 = 0.f, a1 = 0.f, a2 = 0.f, a3 = 0.f;
      for (int j = 0; j < Hh; ++j) {
        float c = bco[j] * U[j * US + pA];
        float4 tq = *(const float4*)&U[j * US + qA];
        a0 = fmaf(c, tq.x, a0);
        a1 = fmaf(c, tq.y, a1);
        a2 = fmaf(c, tq.z, a2);
        a3 = fmaf(c, tq.w, a3);
      }
      Apart[0] += a0; Apart[1] += a1; Apart[2] += a2; Apart[3] += a3;
    }
    __syncthreads();

    // ---- P9: Bq2 reduce ----
    if (t < Nn) {
      float bq = 0.f;
      #pragma unroll
      for (int g = 0; g < 8; ++g) bq += bufA[g * 32 + t];
      Bqv[t] += bq;
    }
    __syncthreads();
  }

  // ---- finalize A (+2I) and rhs ----
  Aug[pA][qA + 0] = Apart[0];
  Aug[pA][qA + 1] = Apart[1];
  Aug[pA][qA + 2] = Apart[2];
  Aug[pA][qA + 3] = Apart[3];
  __syncthreads();
  if (t < Nn) {
    Aug[t][t] += 2.0f;
    Aug[t][Nn] = jacv[t] - Bqv[t];
  }
  __syncthreads();

  // ---- Gauss-Jordan, partial pivot (wave0 shuffle argmax), 2 barriers/step ----
  for (int step = 0; step < Nn; ++step) {
    if (t < 64) {
      int r = t & 31;
      float v = (t < 32 && r >= step) ? fabsf(Aug[r][step]) : -1.f;
      int idx = r;
      #pragma unroll
      for (int m = 16; m; m >>= 1) {
        float ov = __shfl_xor(v, m, 32);
        int oi = __shfl_xor(idx, m, 32);
        if (ov > v) { v = ov; idx = oi; }
      }
      int pv = __shfl(idx, 0, 64);
      if (pv != step && t < 33) {
        float tmp = Aug[step][t];
        Aug[step][t] = Aug[pv][t];
        Aug[pv][t] = tmp;
      }
    }
    __syncthreads();
    {
      int r = t & 31;
      int g = t >> 5;
      float rp = 1.f / Aug[step][step];
      float f = Aug[r][step] * rp;
      if (r != step) {
        #pragma unroll
        for (int u = 0; u < 5; ++u) {
          int c = g + u * 8;
          if (c < 33 && c != step) Aug[r][c] -= f * Aug[step][c];
        }
      }
    }
    __syncthreads();
  }

  if (t < Nn) {
    out[s * Dd + t] = xr[Nn + t];                    // qdot
    out[s * Dd + Nn + t] = Aug[t][Nn] / Aug[t][t];   // qdd
  }
}

extern "C" void kernel_launch(void* const* d_in, const int* in_sizes, int n_in,
                              void* d_out, int out_size, void* d_ws, size_t ws_size,
                              hipStream_t stream) {
  const float* x   = (const float*)d_in[0];
  const float* mW1 = (const float*)d_in[1];
  const float* mb1 = (const float*)d_in[2];
  const float* mW2 = (const float*)d_in[3];
  const float* mb2 = (const float*)d_in[4];
  const float* mW3 = (const float*)d_in[5];
  const float* qW1 = (const float*)d_in[6];
  const float* qb1 = (const float*)d_in[7];
  const float* qW2 = (const float*)d_in[8];
  const float* qb2 = (const float*)d_in[9];
  const float* qW3 = (const float*)d_in[10];

  const int B = in_sizes[0] / Dd;   // 4096
  lnn_kernel<<<dim3(B), dim3(256), 0, stream>>>(
      x, mW1, mb1, mW2, mb2, mW3, qW1, qb1, qW2, qb2, qW3, (float*)d_out);
}

// Round 3
// 766.441 us; speedup vs baseline: 3.0213x; 1.2869x over previous
//
#include <hip/hip_runtime.h>
#include <math.h>

#define Hh 256
#define Dd 64
#define Nn 32
#define TS 264   // Tp stride in shorts (row*TS*2 bytes: 528 % 16 == 0 -> 16B-aligned frags)
#define AS 35    // Aug stride

typedef __attribute__((ext_vector_type(8))) short bf8_t;
typedef __attribute__((ext_vector_type(4))) float f4_t;

__device__ __forceinline__ short f2bf(float f) {
  union { float f; unsigned u; } v; v.f = f;
  unsigned r = v.u + 0x7FFFu + ((v.u >> 16) & 1u);
  return (short)(r >> 16);
}
__device__ __forceinline__ float bf2f(short s) {
  union { unsigned u; float f; } v;
  v.u = ((unsigned)(unsigned short)s) << 16;
  return v.f;
}
__device__ __forceinline__ bf8_t pack8(f4_t lo, f4_t hi) {
  bf8_t r;
  r[0] = f2bf(lo.x); r[1] = f2bf(lo.y); r[2] = f2bf(lo.z); r[3] = f2bf(lo.w);
  r[4] = f2bf(hi.x); r[5] = f2bf(hi.y); r[6] = f2bf(hi.z); r[7] = f2bf(hi.w);
  return r;
}

// ---- pre-pack: W2 -> bf16 B-fragments, W1bot -> fp32 A-fragment layout ----
// ws2 idx = net*65536 + kb*8192 + nt*512 + lane*8 + jj
//   value = bf16( W2[(kb*32 + (lane>>4)*8 + jj)*256 + nt*16 + (lane&15)] )
// ws1 idx = net*8192 + mt*4096 + kb*512 + lane*8 + jj
//   value = W1[(32 + mt*16 + (lane&15))*256 + kb*32 + (lane>>4)*8 + jj]
__global__ void pack_kernel(const float* __restrict__ mW1, const float* __restrict__ mW2,
                            const float* __restrict__ qW1, const float* __restrict__ qW2,
                            short* __restrict__ ws2, float* __restrict__ ws1) {
  int id = blockIdx.x * 256 + threadIdx.x;
  if (id < 131072) {
    int net = id >> 16, r = id & 65535;
    const float* W2 = net ? qW2 : mW2;
    int kb = r >> 13, nt = (r >> 9) & 15, lane = (r >> 3) & 63, jj = r & 7;
    int k = kb * 32 + (lane >> 4) * 8 + jj;
    int j = nt * 16 + (lane & 15);
    ws2[id] = f2bf(W2[k * Hh + j]);
  } else {
    int id2 = id - 131072;
    if (id2 < 16384) {
      int net = id2 >> 13, r = id2 & 8191;
      const float* W1 = net ? qW1 : mW1;
      int mt = r >> 12, kb = (r >> 9) & 7, lane = (r >> 3) & 63, jj = r & 7;
      int m = Nn + mt * 16 + (lane & 15);
      int k = kb * 32 + (lane >> 4) * 8 + jj;
      ws1[id2] = W1[m * Hh + k];
    }
  }
}

__global__ __launch_bounds__(256, 4) void lnn_kernel(
    const float* __restrict__ x,
    const float* __restrict__ mW1, const float* __restrict__ mb1,
    const float* __restrict__ mW2, const float* __restrict__ mb2,
    const float* __restrict__ mW3,
    const float* __restrict__ qW1, const float* __restrict__ qb1,
    const float* __restrict__ qW2, const float* __restrict__ qb2,
    const float* __restrict__ qW3,
    const short* __restrict__ ws2, const float* __restrict__ ws1,
    float* __restrict__ out)
{
  const int s = blockIdx.x;
  const int t = threadIdx.x;
  const int w = t >> 6;        // wave 0..3
  const int lane = t & 63;
  const int q = lane >> 4;     // quad 0..3
  const int ln16 = lane & 15;

  __shared__ __align__(16) float xr[Dd];
  __shared__ __align__(16) float act1[Hh], d2a[Hh], s2[Hh], bco[Hh];
  __shared__ __align__(16) float uarr[Hh], aarr[Hh], rbuf[Hh], bufA[Hh], bufB[Hh];
  __shared__ __align__(16) short Tp[Nn * TS];
  __shared__ float jacv[Nn], Bqv[Nn];
  __shared__ float Aug[Nn][AS];

  if (t < Dd) xr[t] = x[s * Dd + t];
  if (t < Nn) { jacv[t] = 0.f; Bqv[t] = 0.f; }
  __syncthreads();

  f4_t sacc = {0.f, 0.f, 0.f, 0.f};      // SYRK C-tile, accumulated across both nets
  const int mtS = w >> 1, ntS = w & 1;

  for (int net = 0; net < 2; ++net) {
    const float* W1 = net ? qW1 : mW1;
    const float* b1 = net ? qb1 : mb1;
    const float* W2 = net ? qW2 : mW2;
    const float* b2 = net ? qb2 : mb2;
    const float* W3 = net ? qW3 : mW3;

    // ---- P0 (net 1 only): reduce Bq2 partials of net 0 from uarr ----
    if (net == 1 && t < Nn) {
      float bq = 0.f;
      #pragma unroll
      for (int g = 0; g < 8; ++g) bq += uarr[g * 32 + t];
      Bqv[t] += bq;
    }

    // ---- P1: z1 -> h1(bufA), act1, d2a ----
    {
      float z = b1[t];
      #pragma unroll 8
      for (int i = 0; i < Dd; ++i) z = fmaf(xr[i], W1[i * Hh + t], z);
      float f0, f1, f2;
      if (net == 0) {
        float e = __expf(-z);
        float sg = 1.f / (1.f + e);
        f0 = (z > 20.f) ? z : __logf(1.f + __expf(z));
        f1 = sg; f2 = sg * (1.f - sg);
      } else {
        float az = fabsf(z);
        float e = __expf(-az);
        float th = (1.f - e) / (1.f + e);
        th = (z < 0.f) ? -th : th;
        float sech2 = 1.f - th * th;
        f0 = z * th;
        f1 = th + 0.5f * z * sech2;
        f2 = sech2 * (1.f - 0.5f * z * th);
      }
      bufA[t] = f0; act1[t] = f1; d2a[t] = f2;
    }
    __syncthreads();

    // ---- P2: z2 -> s2, bco ; rbuf = W1top^T qdot ----
    {
      float z2 = b2[t];
      for (int k = 0; k < Hh; k += 4) {
        float4 h = *(const float4*)&bufA[k];
        z2 = fmaf(h.x, W2[(k    ) * Hh + t], z2);
        z2 = fmaf(h.y, W2[(k + 1) * Hh + t], z2);
        z2 = fmaf(h.z, W2[(k + 2) * Hh + t], z2);
        z2 = fmaf(h.w, W2[(k + 3) * Hh + t], z2);
      }
      float w3t = W3[t];
      float g1, g2v;
      if (net == 0) {
        float e = __expf(-z2);
        float sg = 1.f / (1.f + e);
        g1 = sg; g2v = sg * (1.f - sg);
      } else {
        float az = fabsf(z2);
        float e = __expf(-az);
        float th = (1.f - e) / (1.f + e);
        th = (z2 < 0.f) ? -th : th;
        float sech2 = 1.f - th * th;
        g1 = th + 0.5f * z2 * sech2;
        g2v = sech2 * (1.f - 0.5f * z2 * th);
      }
      s2[t] = w3t * g1; bco[t] = w3t * g2v;
      float racc = 0.f;
      #pragma unroll 8
      for (int i = 0; i < Nn; ++i) racc = fmaf(xr[Nn + i], W1[i * Hh + t], racc);
      rbuf[t] = racc;
    }
    __syncthreads();

    // ---- P3: v = W2 s2 -> uarr = act1*v, aarr = d2a*v ; bufB = act1*rbuf ----
    {
      float acc = 0.f;
      const float* wr = W2 + t * Hh;
      for (int j = 0; j < Hh; j += 4) {
        float4 wv = *(const float4*)(wr + j);
        float4 sv = *(const float4*)&s2[j];
        acc = fmaf(wv.x, sv.x, acc);
        acc = fmaf(wv.y, sv.y, acc);
        acc = fmaf(wv.z, sv.z, acc);
        acc = fmaf(wv.w, sv.w, acc);
      }
      uarr[t] = act1[t] * acc;
      aarr[t] = d2a[t] * acc;
      bufB[t] = act1[t] * rbuf[t];
    }
    __syncthreads();

    // ---- P4: twv -> s2 ; jac->bufA, Bq1->d2a ; T-GEMM (MFMA) -> Tp ----
    {
      float tacc = 0.f;
      for (int k = 0; k < Hh; k += 4) {
        float4 uv = *(const float4*)&bufB[k];
        tacc = fmaf(uv.x, W2[(k    ) * Hh + t], tacc);
        tacc = fmaf(uv.y, W2[(k + 1) * Hh + t], tacc);
        tacc = fmaf(uv.z, W2[(k + 2) * Hh + t], tacc);
        tacc = fmaf(uv.w, W2[(k + 3) * Hh + t], tacc);
      }
      s2[t] = bco[t] * tacc;
    }
    {
      int i = t & 31, seg = t >> 5;
      const float* wt = W1 + i * Hh + seg * 32;
      const float* wb = W1 + (Nn + i) * Hh + seg * 32;
      float ja = 0.f, bq = 0.f;
      #pragma unroll 4
      for (int k2 = 0; k2 < 32; ++k2) {
        int kk = seg * 32 + k2;
        ja = fmaf(wt[k2], uarr[kk], ja);
        bq = fmaf(wb[k2], aarr[kk] * rbuf[kk], bq);
      }
      bufA[t] = ja; d2a[t] = bq;
    }
    // T-GEMM: T[m][j] = sum_k (W1bot[m,k]*act1[k]) * W2[k,j], via MFMA 16x16x32
    #pragma unroll
    for (int half = 0; half < 2; ++half) {
      f4_t tacc[2][2];
      #pragma unroll
      for (int a = 0; a < 2; ++a)
        #pragma unroll
        for (int b = 0; b < 2; ++b) tacc[a][b] = (f4_t){0.f, 0.f, 0.f, 0.f};
      for (int kb = 0; kb < 8; ++kb) {
        int kbase = kb * 32 + q * 8;
        f4_t a_lo = *(const f4_t*)&act1[kbase];
        f4_t a_hi = *(const f4_t*)&act1[kbase + 4];
        bf8_t afrag[2];
        #pragma unroll
        for (int mt = 0; mt < 2; ++mt) {
          const f4_t* srcp = (const f4_t*)&ws1[((((net * 2 + mt) * 8) + kb) << 9) + lane * 8];
          f4_t w0 = srcp[0], w1 = srcp[1];
          afrag[mt] = pack8(w0 * a_lo, w1 * a_hi);
        }
        #pragma unroll
        for (int j = 0; j < 2; ++j) {
          int nt = w + (half * 2 + j) * 4;
          bf8_t bf = *(const bf8_t*)&ws2[(((net * 8 + kb) << 4) + nt) * 512 + lane * 8];
          tacc[0][j] = __builtin_amdgcn_mfma_f32_16x16x32_bf16(afrag[0], bf, tacc[0][j], 0, 0, 0);
          tacc[1][j] = __builtin_amdgcn_mfma_f32_16x16x32_bf16(afrag[1], bf, tacc[1][j], 0, 0, 0);
        }
      }
      #pragma unroll
      for (int mt = 0; mt < 2; ++mt)
        #pragma unroll
        for (int j = 0; j < 2; ++j) {
          int nt = w + (half * 2 + j) * 4;
          int col = nt * 16 + ln16;
          int rowb = mt * 16 + q * 4;
          Tp[(rowb + 0) * TS + col] = f2bf(tacc[mt][j][0]);
          Tp[(rowb + 1) * TS + col] = f2bf(tacc[mt][j][1]);
          Tp[(rowb + 2) * TS + col] = f2bf(tacc[mt][j][2]);
          Tp[(rowb + 3) * TS + col] = f2bf(tacc[mt][j][3]);
        }
    }
    __syncthreads();

    // ---- P5: reduce jac/Bq1 ; Bq2 partial -> uarr ; SYRK (MFMA) ----
    if (t < Nn) {
      float ja = 0.f, bq = 0.f;
      #pragma unroll
      for (int g = 0; g < 8; ++g) { ja += bufA[g * 32 + t]; bq += d2a[g * 32 + t]; }
      jacv[t] += ja; Bqv[t] += bq;
    }
    {
      int p = t & 31, seg = t >> 5;
      float acc = 0.f;
      #pragma unroll 4
      for (int j2 = 0; j2 < 32; ++j2) {
        int j = seg * 32 + j2;
        acc = fmaf(bf2f(Tp[p * TS + j]), s2[j], acc);
      }
      uarr[t] = acc;
    }
    // SYRK W-term: A += (W1bot*aarr) W1bot^T
    for (int kb = 0; kb < 8; ++kb) {
      int kbase = kb * 32 + q * 8;
      f4_t aa0 = *(const f4_t*)&aarr[kbase];
      f4_t aa1 = *(const f4_t*)&aarr[kbase + 4];
      const f4_t* am = (const f4_t*)&ws1[((((net * 2 + mtS) * 8) + kb) << 9) + lane * 8];
      const f4_t* bn = (const f4_t*)&ws1[((((net * 2 + ntS) * 8) + kb) << 9) + lane * 8];
      f4_t m0 = am[0], m1 = am[1];
      f4_t n0 = bn[0], n1 = bn[1];
      bf8_t afr = pack8(m0 * aa0, m1 * aa1);
      bf8_t bfr = pack8(n0, n1);
      sacc = __builtin_amdgcn_mfma_f32_16x16x32_bf16(afr, bfr, sacc, 0, 0, 0);
    }
    // SYRK T-term: A += (T*bco) T^T
    for (int jb = 0; jb < 8; ++jb) {
      int jbase = jb * 32 + q * 8;
      f4_t bc0 = *(const f4_t*)&bco[jbase];
      f4_t bc1 = *(const f4_t*)&bco[jbase + 4];
      bf8_t ta = *(const bf8_t*)&Tp[(mtS * 16 + ln16) * TS + jbase];
      bf8_t tb = *(const bf8_t*)&Tp[(ntS * 16 + ln16) * TS + jbase];
      bf8_t afr;
      afr[0] = f2bf(bf2f(ta[0]) * bc0.x);
      afr[1] = f2bf(bf2f(ta[1]) * bc0.y);
      afr[2] = f2bf(bf2f(ta[2]) * bc0.z);
      afr[3] = f2bf(bf2f(ta[3]) * bc0.w);
      afr[4] = f2bf(bf2f(ta[4]) * bc1.x);
      afr[5] = f2bf(bf2f(ta[5]) * bc1.y);
      afr[6] = f2bf(bf2f(ta[6]) * bc1.z);
      afr[7] = f2bf(bf2f(ta[7]) * bc1.w);
      sacc = __builtin_amdgcn_mfma_f32_16x16x32_bf16(afr, tb, sacc, 0, 0, 0);
    }
    __syncthreads();
  }

  // ---- final Bq2 reduce (net 1) ----
  if (t < Nn) {
    float bq = 0.f;
    #pragma unroll
    for (int g = 0; g < 8; ++g) bq += uarr[g * 32 + t];
    Bqv[t] += bq;
  }
  // ---- write SYRK tiles into Aug (C-layout: row=(q*4+r), col=ln16) ----
  {
    int col = ntS * 16 + ln16;
    int rowb = mtS * 16 + q * 4;
    Aug[rowb + 0][col] = sacc[0];
    Aug[rowb + 1][col] = sacc[1];
    Aug[rowb + 2][col] = sacc[2];
    Aug[rowb + 3][col] = sacc[3];
  }
  __syncthreads();
  if (t < Nn) {
    Aug[t][t] += 2.0f;
    Aug[t][Nn] = jacv[t] - Bqv[t];
  }
  __syncthreads();

  // ---- Gauss-Jordan, partial pivot (wave0 shuffle argmax), 2 barriers/step ----
  for (int step = 0; step < Nn; ++step) {
    if (t < 64) {
      int r = t & 31;
      float v = (t < 32 && r >= step) ? fabsf(Aug[r][step]) : -1.f;
      int idx = r;
      #pragma unroll
      for (int m = 16; m; m >>= 1) {
        float ov = __shfl_xor(v, m, 32);
        int oi = __shfl_xor(idx, m, 32);
        if (ov > v) { v = ov; idx = oi; }
      }
      int pv = __shfl(idx, 0, 64);
      if (pv != step && t < 33) {
        float tmp = Aug[step][t];
        Aug[step][t] = Aug[pv][t];
        Aug[pv][t] = tmp;
      }
    }
    __syncthreads();
    {
      int r = t & 31;
      int g = t >> 5;
      float rp = 1.f / Aug[step][step];
      float f = Aug[r][step] * rp;
      if (r != step) {
        #pragma unroll
        for (int u = 0; u < 5; ++u) {
          int c = g + u * 8;
          if (c < 33 && c != step) Aug[r][c] -= f * Aug[step][c];
        }
      }
    }
    __syncthreads();
  }

  if (t < Nn) {
    out[s * Dd + t] = xr[Nn + t];                    // qdot
    out[s * Dd + Nn + t] = Aug[t][Nn] / Aug[t][t];   // qdd
  }
}

extern "C" void kernel_launch(void* const* d_in, const int* in_sizes, int n_in,
                              void* d_out, int out_size, void* d_ws, size_t ws_size,
                              hipStream_t stream) {
  const float* x   = (const float*)d_in[0];
  const float* mW1 = (const float*)d_in[1];
  const float* mb1 = (const float*)d_in[2];
  const float* mW2 = (const float*)d_in[3];
  const float* mb2 = (const float*)d_in[4];
  const float* mW3 = (const float*)d_in[5];
  const float* qW1 = (const float*)d_in[6];
  const float* qb1 = (const float*)d_in[7];
  const float* qW2 = (const float*)d_in[8];
  const float* qb2 = (const float*)d_in[9];
  const float* qW3 = (const float*)d_in[10];

  short* ws2 = (short*)d_ws;                          // 2 x 65536 bf16 = 256 KB
  float* ws1 = (float*)((char*)d_ws + 262144);        // 2 x 8192 fp32 = 64 KB

  pack_kernel<<<dim3(576), dim3(256), 0, stream>>>(mW1, mW2, qW1, qW2, ws2, ws1);

  const int B = in_sizes[0] / Dd;   // 4096
  lnn_kernel<<<dim3(B), dim3(256), 0, stream>>>(
      x, mW1, mb1, mW2, mb2, mW3, qW1, qb1, qW2, qb2, qW3, ws2, ws1, (float*)d_out);
}

// Round 4
// 654.938 us; speedup vs baseline: 3.5356x; 1.1702x over previous
//
#include <hip/hip_runtime.h>
#include <math.h>

#define Hh 256
#define Dd 64
#define Nn 32
#define TS 264   // Tp stride in shorts (row*TS*2 bytes: 528 % 16 == 0 -> 16B-aligned frags)
#define AS 35    // Aug stride

typedef __attribute__((ext_vector_type(8))) short bf8_t;
typedef __attribute__((ext_vector_type(4))) float f4_t;

__device__ __forceinline__ short f2bf(float f) {
  union { float f; unsigned u; } v; v.f = f;
  unsigned r = v.u + 0x7FFFu + ((v.u >> 16) & 1u);
  return (short)(r >> 16);
}
__device__ __forceinline__ float bf2f(short s) {
  union { unsigned u; float f; } v;
  v.u = ((unsigned)(unsigned short)s) << 16;
  return v.f;
}
__device__ __forceinline__ bf8_t pack8(f4_t lo, f4_t hi) {
  bf8_t r;
  r[0] = f2bf(lo.x); r[1] = f2bf(lo.y); r[2] = f2bf(lo.z); r[3] = f2bf(lo.w);
  r[4] = f2bf(hi.x); r[5] = f2bf(hi.y); r[6] = f2bf(hi.z); r[7] = f2bf(hi.w);
  return r;
}
__device__ __forceinline__ void bf8_to_f(bf8_t v, f4_t& lo, f4_t& hi) {
  lo.x = bf2f(v[0]); lo.y = bf2f(v[1]); lo.z = bf2f(v[2]); lo.w = bf2f(v[3]);
  hi.x = bf2f(v[4]); hi.y = bf2f(v[5]); hi.z = bf2f(v[6]); hi.w = bf2f(v[7]);
}

// ---- pre-pack ----
// ws4[net*65536 + c*256 + k] = bf16(W2[k][c])   (column-c contiguous in k)
//   serves: z2/twv GEMVs (row-contig bf16x8), v GEMV (coalesced ushort),
//           MFMA B-frags: B[k=kb*32+q*8+jj][n=nt*16+ln16] = ws4[n*256 + kb*32+q*8+jj]
// ws1[((net*2+mt)*8+kb)*512 + lane*8 + jj] = bf16(W1[32+mt*16+(lane&15)][kb*32+(lane>>4)*8+jj])
__global__ void pack_kernel(const float* __restrict__ mW1, const float* __restrict__ mW2,
                            const float* __restrict__ qW1, const float* __restrict__ qW2,
                            short* __restrict__ ws4, short* __restrict__ ws1) {
  int id = blockIdx.x * 256 + threadIdx.x;
  if (id < 131072) {
    int net = id >> 16;
    const float* W2 = net ? qW2 : mW2;
    int c = (id >> 8) & 255, k = id & 255;
    ws4[id] = f2bf(W2[k * Hh + c]);
  } else {
    int id2 = id - 131072;
    if (id2 < 16384) {
      int net = id2 >> 13, r = id2 & 8191;
      const float* W1 = net ? qW1 : mW1;
      int mt = r >> 12, kb = (r >> 9) & 7, lane = (r >> 3) & 63, jj = r & 7;
      int m = Nn + mt * 16 + (lane & 15);
      int k = kb * 32 + (lane >> 4) * 8 + jj;
      ws1[id2] = f2bf(W1[m * Hh + k]);
    }
  }
}

__global__ __launch_bounds__(256, 3) void lnn_kernel(
    const float* __restrict__ x,
    const float* __restrict__ mW1, const float* __restrict__ mb1,
    const float* __restrict__ mW2, const float* __restrict__ mb2,
    const float* __restrict__ mW3,
    const float* __restrict__ qW1, const float* __restrict__ qb1,
    const float* __restrict__ qW2, const float* __restrict__ qb2,
    const float* __restrict__ qW3,
    const short* __restrict__ ws4, const short* __restrict__ ws1,
    float* __restrict__ out)
{
  const int s = blockIdx.x;
  const int t = threadIdx.x;
  const int w = t >> 6;        // wave 0..3
  const int lane = t & 63;
  const int q = lane >> 4;     // quad 0..3
  const int ln16 = lane & 15;

  __shared__ __align__(16) float xr[Dd];
  __shared__ __align__(16) float act1[Hh], d2a[Hh], s2[Hh], bco[Hh];
  __shared__ __align__(16) float uarr[Hh], aarr[Hh], rbuf[Hh], bufA[Hh], bufB[Hh];
  __shared__ __align__(16) short Tp[Nn * TS];
  __shared__ float jacv[Nn], Bqv[Nn];
  __shared__ float Aug[Nn][AS];

  if (t < Dd) xr[t] = x[s * Dd + t];
  if (t < Nn) { jacv[t] = 0.f; Bqv[t] = 0.f; }
  __syncthreads();

  f4_t sacc = {0.f, 0.f, 0.f, 0.f};      // SYRK C-tile, accumulated across both nets
  const int mtS = w >> 1, ntS = w & 1;

  for (int net = 0; net < 2; ++net) {
    const float* W1 = net ? qW1 : mW1;
    const float* b1 = net ? qb1 : mb1;
    const float* b2 = net ? qb2 : mb2;
    const float* W3 = net ? qW3 : mW3;
    const short* w4 = ws4 + net * 65536;

    // ---- P0 (net 1 only): reduce Bq2 partials of net 0 from uarr ----
    if (net == 1 && t < Nn) {
      float bq = 0.f;
      #pragma unroll
      for (int g = 0; g < 8; ++g) bq += uarr[g * 32 + t];
      Bqv[t] += bq;
    }

    // ---- P1: z1 -> h1(bufA), act1, d2a ----
    {
      float z = b1[t];
      #pragma unroll 8
      for (int i = 0; i < Dd; ++i) z = fmaf(xr[i], W1[i * Hh + t], z);
      float f0, f1, f2;
      if (net == 0) {
        float e = __expf(-z);
        float sg = 1.f / (1.f + e);
        f0 = (z > 20.f) ? z : __logf(1.f + __expf(z));
        f1 = sg; f2 = sg * (1.f - sg);
      } else {
        float az = fabsf(z);
        float e = __expf(-az);
        float th = (1.f - e) / (1.f + e);
        th = (z < 0.f) ? -th : th;
        float sech2 = 1.f - th * th;
        f0 = z * th;
        f1 = th + 0.5f * z * sech2;
        f2 = sech2 * (1.f - 0.5f * z * th);
      }
      bufA[t] = f0; act1[t] = f1; d2a[t] = f2;
    }
    __syncthreads();

    // ---- P2: z2 -> s2, bco ; rbuf = W1top^T qdot ----
    {
      float z2 = b2[t];
      const short* wcol = w4 + t * Hh;       // column t of W2, contiguous in k
      for (int kb = 0; kb < 32; ++kb) {
        bf8_t wv = *(const bf8_t*)&wcol[kb * 8];
        f4_t lo, hi; bf8_to_f(wv, lo, hi);
        float4 h0 = *(const float4*)&bufA[kb * 8];
        float4 h1v = *(const float4*)&bufA[kb * 8 + 4];
        z2 = fmaf(lo.x, h0.x, z2);  z2 = fmaf(lo.y, h0.y, z2);
        z2 = fmaf(lo.z, h0.z, z2);  z2 = fmaf(lo.w, h0.w, z2);
        z2 = fmaf(hi.x, h1v.x, z2); z2 = fmaf(hi.y, h1v.y, z2);
        z2 = fmaf(hi.z, h1v.z, z2); z2 = fmaf(hi.w, h1v.w, z2);
      }
      float w3t = W3[t];
      float g1, g2v;
      if (net == 0) {
        float e = __expf(-z2);
        float sg = 1.f / (1.f + e);
        g1 = sg; g2v = sg * (1.f - sg);
      } else {
        float az = fabsf(z2);
        float e = __expf(-az);
        float th = (1.f - e) / (1.f + e);
        th = (z2 < 0.f) ? -th : th;
        float sech2 = 1.f - th * th;
        g1 = th + 0.5f * z2 * sech2;
        g2v = sech2 * (1.f - 0.5f * z2 * th);
      }
      s2[t] = w3t * g1; bco[t] = w3t * g2v;
      float racc = 0.f;
      #pragma unroll 8
      for (int i = 0; i < Nn; ++i) racc = fmaf(xr[Nn + i], W1[i * Hh + t], racc);
      rbuf[t] = racc;
    }
    __syncthreads();

    // ---- P3: v_t = W2[t][:] . s2 -> uarr = act1*v, aarr = d2a*v ; bufB = act1*rbuf ----
    {
      float acc = 0.f;
      const short* wrow = w4 + t;            // W2[t][j] = ws4[j*256+t], coalesced
      for (int j = 0; j < Hh; j += 4) {
        float4 sv = *(const float4*)&s2[j];
        acc = fmaf(bf2f(wrow[(j    ) * Hh]), sv.x, acc);
        acc = fmaf(bf2f(wrow[(j + 1) * Hh]), sv.y, acc);
        acc = fmaf(bf2f(wrow[(j + 2) * Hh]), sv.z, acc);
        acc = fmaf(bf2f(wrow[(j + 3) * Hh]), sv.w, acc);
      }
      uarr[t] = act1[t] * acc;
      aarr[t] = d2a[t] * acc;
      bufB[t] = act1[t] * rbuf[t];
    }
    __syncthreads();

    // ---- P4: twv -> s2 ; jac->bufA, Bq1->d2a ; T-GEMM (MFMA) -> Tp ----
    {
      float tacc = 0.f;
      const short* wcol = w4 + t * Hh;
      for (int kb = 0; kb < 32; ++kb) {
        bf8_t wv = *(const bf8_t*)&wcol[kb * 8];
        f4_t lo, hi; bf8_to_f(wv, lo, hi);
        float4 u0 = *(const float4*)&bufB[kb * 8];
        float4 u1 = *(const float4*)&bufB[kb * 8 + 4];
        tacc = fmaf(lo.x, u0.x, tacc);  tacc = fmaf(lo.y, u0.y, tacc);
        tacc = fmaf(lo.z, u0.z, tacc);  tacc = fmaf(lo.w, u0.w, tacc);
        tacc = fmaf(hi.x, u1.x, tacc);  tacc = fmaf(hi.y, u1.y, tacc);
        tacc = fmaf(hi.z, u1.z, tacc);  tacc = fmaf(hi.w, u1.w, tacc);
      }
      s2[t] = bco[t] * tacc;
    }
    {
      int i = t & 31, seg = t >> 5;
      const float* wt = W1 + i * Hh + seg * 32;
      const float* wb = W1 + (Nn + i) * Hh + seg * 32;
      float ja = 0.f, bq = 0.f;
      #pragma unroll 4
      for (int k2 = 0; k2 < 32; ++k2) {
        int kk = seg * 32 + k2;
        ja = fmaf(wt[k2], uarr[kk], ja);
        bq = fmaf(wb[k2], aarr[kk] * rbuf[kk], bq);
      }
      bufA[t] = ja; d2a[t] = bq;
    }
    // T-GEMM: T[m][j] = sum_k (W1bot[m,k]*act1[k]) * W2[k,j], via MFMA 16x16x32
    #pragma unroll
    for (int half = 0; half < 2; ++half) {
      f4_t tacc[2][2];
      #pragma unroll
      for (int a = 0; a < 2; ++a)
        #pragma unroll
        for (int b = 0; b < 2; ++b) tacc[a][b] = (f4_t){0.f, 0.f, 0.f, 0.f};
      for (int kb = 0; kb < 8; ++kb) {
        int kbase = kb * 32 + q * 8;
        f4_t a_lo = *(const f4_t*)&act1[kbase];
        f4_t a_hi = *(const f4_t*)&act1[kbase + 4];
        bf8_t afrag[2];
        #pragma unroll
        for (int mt = 0; mt < 2; ++mt) {
          bf8_t w8 = *(const bf8_t*)&ws1[((((net * 2 + mt) * 8) + kb) << 9) + lane * 8];
          f4_t lo, hi; bf8_to_f(w8, lo, hi);
          afrag[mt] = pack8(lo * a_lo, hi * a_hi);
        }
        #pragma unroll
        for (int j = 0; j < 2; ++j) {
          int nt = w + (half * 2 + j) * 4;
          bf8_t bf = *(const bf8_t*)&w4[(nt * 16 + ln16) * Hh + kbase];
          tacc[0][j] = __builtin_amdgcn_mfma_f32_16x16x32_bf16(afrag[0], bf, tacc[0][j], 0, 0, 0);
          tacc[1][j] = __builtin_amdgcn_mfma_f32_16x16x32_bf16(afrag[1], bf, tacc[1][j], 0, 0, 0);
        }
      }
      #pragma unroll
      for (int mt = 0; mt < 2; ++mt)
        #pragma unroll
        for (int j = 0; j < 2; ++j) {
          int nt = w + (half * 2 + j) * 4;
          int col = nt * 16 + ln16;
          int rowb = mt * 16 + q * 4;
          Tp[(rowb + 0) * TS + col] = f2bf(tacc[mt][j][0]);
          Tp[(rowb + 1) * TS + col] = f2bf(tacc[mt][j][1]);
          Tp[(rowb + 2) * TS + col] = f2bf(tacc[mt][j][2]);
          Tp[(rowb + 3) * TS + col] = f2bf(tacc[mt][j][3]);
        }
    }
    __syncthreads();

    // ---- P5: reduce jac/Bq1 ; Bq2 partial -> uarr ; SYRK (MFMA) ----
    if (t < Nn) {
      float ja = 0.f, bq = 0.f;
      #pragma unroll
      for (int g = 0; g < 8; ++g) { ja += bufA[g * 32 + t]; bq += d2a[g * 32 + t]; }
      jacv[t] += ja; Bqv[t] += bq;
    }
    {
      int p = t & 31, seg = t >> 5;
      float acc = 0.f;
      #pragma unroll 4
      for (int j2 = 0; j2 < 32; ++j2) {
        int j = seg * 32 + j2;
        acc = fmaf(bf2f(Tp[p * TS + j]), s2[j], acc);
      }
      uarr[t] = acc;
    }
    // SYRK W-term: A += (W1bot*aarr) W1bot^T
    for (int kb = 0; kb < 8; ++kb) {
      int kbase = kb * 32 + q * 8;
      f4_t aa0 = *(const f4_t*)&aarr[kbase];
      f4_t aa1 = *(const f4_t*)&aarr[kbase + 4];
      bf8_t am8 = *(const bf8_t*)&ws1[((((net * 2 + mtS) * 8) + kb) << 9) + lane * 8];
      bf8_t bn8 = *(const bf8_t*)&ws1[((((net * 2 + ntS) * 8) + kb) << 9) + lane * 8];
      f4_t lo, hi; bf8_to_f(am8, lo, hi);
      bf8_t afr = pack8(lo * aa0, hi * aa1);
      sacc = __builtin_amdgcn_mfma_f32_16x16x32_bf16(afr, bn8, sacc, 0, 0, 0);
    }
    // SYRK T-term: A += (T*bco) T^T
    for (int jb = 0; jb < 8; ++jb) {
      int jbase = jb * 32 + q * 8;
      f4_t bc0 = *(const f4_t*)&bco[jbase];
      f4_t bc1 = *(const f4_t*)&bco[jbase + 4];
      bf8_t ta = *(const bf8_t*)&Tp[(mtS * 16 + ln16) * TS + jbase];
      bf8_t tb = *(const bf8_t*)&Tp[(ntS * 16 + ln16) * TS + jbase];
      bf8_t afr;
      afr[0] = f2bf(bf2f(ta[0]) * bc0.x);
      afr[1] = f2bf(bf2f(ta[1]) * bc0.y);
      afr[2] = f2bf(bf2f(ta[2]) * bc0.z);
      afr[3] = f2bf(bf2f(ta[3]) * bc0.w);
      afr[4] = f2bf(bf2f(ta[4]) * bc1.x);
      afr[5] = f2bf(bf2f(ta[5]) * bc1.y);
      afr[6] = f2bf(bf2f(ta[6]) * bc1.z);
      afr[7] = f2bf(bf2f(ta[7]) * bc1.w);
      sacc = __builtin_amdgcn_mfma_f32_16x16x32_bf16(afr, tb, sacc, 0, 0, 0);
    }
    __syncthreads();
  }

  // ---- final Bq2 reduce (net 1) ----
  if (t < Nn) {
    float bq = 0.f;
    #pragma unroll
    for (int g = 0; g < 8; ++g) bq += uarr[g * 32 + t];
    Bqv[t] += bq;
  }
  // ---- write SYRK tiles into Aug (C-layout: row=(q*4+r), col=ln16) ----
  {
    int col = ntS * 16 + ln16;
    int rowb = mtS * 16 + q * 4;
    Aug[rowb + 0][col] = sacc[0];
    Aug[rowb + 1][col] = sacc[1];
    Aug[rowb + 2][col] = sacc[2];
    Aug[rowb + 3][col] = sacc[3];
  }
  __syncthreads();
  if (t < Nn) {
    Aug[t][t] += 2.0f;
    Aug[t][Nn] = jacv[t] - Bqv[t];
  }
  __syncthreads();

  // ---- single-wave register Gauss-Jordan, no pivot (A = 2I + small), 0 barriers ----
  if (t < 32) {
    float a[Nn + 1];
    #pragma unroll
    for (int c = 0; c <= Nn; ++c) a[c] = Aug[t][c];
    float mydiag = 1.f;
    #pragma unroll
    for (int st = 0; st < Nn; ++st) {
      float pd = __shfl(a[st], st, 64);
      mydiag = (t == st) ? pd : mydiag;
      float f = a[st] / pd;
      bool self = (t == st);
      #pragma unroll
      for (int c = st + 1; c <= Nn; ++c) {
        float pc = __shfl(a[c], st, 64);
        if (!self) a[c] = fmaf(-f, pc, a[c]);
      }
    }
    out[s * Dd + t] = xr[Nn + t];              // qdot
    out[s * Dd + Nn + t] = a[Nn] / mydiag;     // qdd
  }
}

extern "C" void kernel_launch(void* const* d_in, const int* in_sizes, int n_in,
                              void* d_out, int out_size, void* d_ws, size_t ws_size,
                              hipStream_t stream) {
  const float* x   = (const float*)d_in[0];
  const float* mW1 = (const float*)d_in[1];
  const float* mb1 = (const float*)d_in[2];
  const float* mW2 = (const float*)d_in[3];
  const float* mb2 = (const float*)d_in[4];
  const float* mW3 = (const float*)d_in[5];
  const float* qW1 = (const float*)d_in[6];
  const float* qb1 = (const float*)d_in[7];
  const float* qW2 = (const float*)d_in[8];
  const float* qb2 = (const float*)d_in[9];
  const float* qW3 = (const float*)d_in[10];

  short* ws4 = (short*)d_ws;                          // 2 x 65536 bf16 = 256 KB
  short* ws1 = (short*)((char*)d_ws + 262144);        // 2 x 8192 bf16 = 32 KB

  pack_kernel<<<dim3(576), dim3(256), 0, stream>>>(mW1, mW2, qW1, qW2, ws4, ws1);

  const int B = in_sizes[0] / Dd;   // 4096
  lnn_kernel<<<dim3(B), dim3(256), 0, stream>>>(
      x, mW1, mb1, mW2, mb2, mW3, qW1, qb1, qW2, qb2, qW3, ws4, ws1, (float*)d_out);
}

// Round 5
// 475.607 us; speedup vs baseline: 4.8688x; 1.3771x over previous
//
#include <hip/hip_runtime.h>
#include <math.h>

#define Hh 256
#define Dd 64
#define Nn 32
#define TS 264   // Tp stride in shorts (row*TS*2 = 528 bytes, 16B-aligned)
#define AS 35    // Aug stride

typedef __attribute__((ext_vector_type(8))) short bf8_t;
typedef __attribute__((ext_vector_type(4))) float f4_t;

__device__ __forceinline__ short f2bf(float f) {
  union { float f; unsigned u; } v; v.f = f;
  unsigned r = v.u + 0x7FFFu + ((v.u >> 16) & 1u);
  return (short)(r >> 16);
}
__device__ __forceinline__ float bf2f(short s) {
  union { unsigned u; float f; } v;
  v.u = ((unsigned)(unsigned short)s) << 16;
  return v.f;
}
__device__ __forceinline__ bf8_t pack8(f4_t lo, f4_t hi) {
  bf8_t r;
  r[0] = f2bf(lo.x); r[1] = f2bf(lo.y); r[2] = f2bf(lo.z); r[3] = f2bf(lo.w);
  r[4] = f2bf(hi.x); r[5] = f2bf(hi.y); r[6] = f2bf(hi.z); r[7] = f2bf(hi.w);
  return r;
}
__device__ __forceinline__ void bf8_to_f(bf8_t v, f4_t& lo, f4_t& hi) {
  lo.x = bf2f(v[0]); lo.y = bf2f(v[1]); lo.z = bf2f(v[2]); lo.w = bf2f(v[3]);
  hi.x = bf2f(v[4]); hi.y = bf2f(v[5]); hi.z = bf2f(v[6]); hi.w = bf2f(v[7]);
}
__device__ __forceinline__ void act012(int net, float z, float& f0, float& f1, float& f2) {
  if (net == 0) {
    float e = __expf(-z);
    float sg = 1.f / (1.f + e);
    f0 = (z > 20.f) ? z : __logf(1.f + __expf(z));
    f1 = sg; f2 = sg * (1.f - sg);
  } else {
    float az = fabsf(z);
    float e = __expf(-az);
    float th = (1.f - e) / (1.f + e);
    th = (z < 0.f) ? -th : th;
    float sech2 = 1.f - th * th;
    f0 = z * th;
    f1 = th + 0.5f * z * sech2;
    f2 = sech2 * (1.f - 0.5f * z * th);
  }
}
__device__ __forceinline__ void act12(int net, float z, float& g1, float& g2) {
  if (net == 0) {
    float e = __expf(-z);
    float sg = 1.f / (1.f + e);
    g1 = sg; g2 = sg * (1.f - sg);
  } else {
    float az = fabsf(z);
    float e = __expf(-az);
    float th = (1.f - e) / (1.f + e);
    th = (z < 0.f) ? -th : th;
    float sech2 = 1.f - th * th;
    g1 = th + 0.5f * z * sech2;
    g2 = sech2 * (1.f - 0.5f * z * th);
  }
}

// ---- pre-pack ----
// ws4[net*65536 + c*256 + k]             = bf16(W2[k][c])       (columns contiguous in k)
// ws1[((net*2+mt)*8+kb)*512 + lane*8+jj] = bf16(W1[32+mt*16+(lane&15)][kb*32+(lane>>4)*8+jj])
// ws6[net*16384 + t*64 + i]              = bf16(W1[i][t])       (W1 columns contiguous)
__global__ void pack_kernel(const float* __restrict__ mW1, const float* __restrict__ mW2,
                            const float* __restrict__ qW1, const float* __restrict__ qW2,
                            short* __restrict__ ws4, short* __restrict__ ws1,
                            short* __restrict__ ws6) {
  int id = blockIdx.x * 256 + threadIdx.x;
  if (id < 131072) {
    int net = id >> 16;
    const float* W2 = net ? qW2 : mW2;
    int c = (id >> 8) & 255, k = id & 255;
    ws4[id] = f2bf(W2[k * Hh + c]);
  } else if (id < 147456) {
    int id2 = id - 131072;
    int net = id2 >> 13, r = id2 & 8191;
    const float* W1 = net ? qW1 : mW1;
    int mt = r >> 12, kb = (r >> 9) & 7, lane = (r >> 3) & 63, jj = r & 7;
    int m = Nn + mt * 16 + (lane & 15);
    int k = kb * 32 + (lane >> 4) * 8 + jj;
    ws1[id2] = f2bf(W1[m * Hh + k]);
  } else if (id < 180224) {
    int id3 = id - 147456;
    int net = id3 >> 14, r = id3 & 16383;
    const float* W1 = net ? qW1 : mW1;
    int tc = r >> 6, i = r & 63;
    ws6[id3] = f2bf(W1[i * Hh + tc]);
  }
}

__global__ __launch_bounds__(256, 2) void lnn_kernel(
    const float* __restrict__ x,
    const float* __restrict__ mW1, const float* __restrict__ mb1,
    const float* __restrict__ mW2, const float* __restrict__ mb2,
    const float* __restrict__ mW3,
    const float* __restrict__ qW1, const float* __restrict__ qb1,
    const float* __restrict__ qW2, const float* __restrict__ qb2,
    const float* __restrict__ qW3,
    const short* __restrict__ ws4, const short* __restrict__ ws1,
    const short* __restrict__ ws6,
    float* __restrict__ out)
{
  const int s0 = blockIdx.x * 2;
  const int t = threadIdx.x;
  const int w = t >> 6;        // wave 0..3
  const int lane = t & 63;
  const int q = lane >> 4;     // quad 0..3
  const int ln16 = lane & 15;

  __shared__ __align__(16) float xr[2][Dd];
  __shared__ __align__(16) float act1[2][Hh], d2a[2][Hh], s2[2][Hh], bco[2][Hh];
  __shared__ __align__(16) float uarr[2][Hh], aarr[2][Hh], rbuf[2][Hh], bufA[2][Hh], bufB[2][Hh];
  __shared__ __align__(16) short Tp[2][Nn * TS];
  __shared__ float jacv[2][Nn], Bqv[2][Nn];
  __shared__ float Aug[2][Nn][AS];

  if (t < 128) ((float*)xr)[t] = x[s0 * Dd + t];
  if (t < 64) { jacv[t >> 5][t & 31] = 0.f; Bqv[t >> 5][t & 31] = 0.f; }
  __syncthreads();

  f4_t sacc[2];
  sacc[0] = (f4_t){0.f, 0.f, 0.f, 0.f};
  sacc[1] = (f4_t){0.f, 0.f, 0.f, 0.f};
  const int mtS = w >> 1, ntS = w & 1;

  for (int net = 0; net < 2; ++net) {
    const float* W1 = net ? qW1 : mW1;
    const float* W2 = net ? qW2 : mW2;
    const float* b1 = net ? qb1 : mb1;
    const float* b2 = net ? qb2 : mb2;
    const float* W3 = net ? qW3 : mW3;
    const short* w4 = ws4 + net * 65536;
    const short* w6 = ws6 + net * 16384 + t * 64;

    // ---- P0 (net 1 only): reduce Bq2 partials of net 0 ----
    if (net == 1 && t < 64) {
      int smp = t >> 5, r = t & 31;
      float bq = 0.f;
      #pragma unroll
      for (int g = 0; g < 8; ++g) bq += uarr[smp][g * 32 + r];
      Bqv[smp][r] += bq;
    }

    // ---- P1: z1 (both samples) + rbuf (both), bf16 W1 columns ----
    {
      float b1t = b1[t];
      float zA = b1t, zB = b1t, rA = 0.f, rB = 0.f;
      #pragma unroll
      for (int ib = 0; ib < 8; ++ib) {
        bf8_t w8 = *(const bf8_t*)&w6[ib * 8];
        f4_t lo, hi; bf8_to_f(w8, lo, hi);
        float4 xa0 = *(const float4*)&xr[0][ib * 8];
        float4 xa1 = *(const float4*)&xr[0][ib * 8 + 4];
        float4 xb0 = *(const float4*)&xr[1][ib * 8];
        float4 xb1 = *(const float4*)&xr[1][ib * 8 + 4];
        zA = fmaf(lo.x, xa0.x, zA); zA = fmaf(lo.y, xa0.y, zA);
        zA = fmaf(lo.z, xa0.z, zA); zA = fmaf(lo.w, xa0.w, zA);
        zA = fmaf(hi.x, xa1.x, zA); zA = fmaf(hi.y, xa1.y, zA);
        zA = fmaf(hi.z, xa1.z, zA); zA = fmaf(hi.w, xa1.w, zA);
        zB = fmaf(lo.x, xb0.x, zB); zB = fmaf(lo.y, xb0.y, zB);
        zB = fmaf(lo.z, xb0.z, zB); zB = fmaf(lo.w, xb0.w, zB);
        zB = fmaf(hi.x, xb1.x, zB); zB = fmaf(hi.y, xb1.y, zB);
        zB = fmaf(hi.z, xb1.z, zB); zB = fmaf(hi.w, xb1.w, zB);
        if (ib < 4) {   // W1 rows 0..31 also feed rbuf with qdot
          float4 qa0 = *(const float4*)&xr[0][Nn + ib * 8];
          float4 qa1 = *(const float4*)&xr[0][Nn + ib * 8 + 4];
          float4 qb0 = *(const float4*)&xr[1][Nn + ib * 8];
          float4 qb1 = *(const float4*)&xr[1][Nn + ib * 8 + 4];
          rA = fmaf(lo.x, qa0.x, rA); rA = fmaf(lo.y, qa0.y, rA);
          rA = fmaf(lo.z, qa0.z, rA); rA = fmaf(lo.w, qa0.w, rA);
          rA = fmaf(hi.x, qa1.x, rA); rA = fmaf(hi.y, qa1.y, rA);
          rA = fmaf(hi.z, qa1.z, rA); rA = fmaf(hi.w, qa1.w, rA);
          rB = fmaf(lo.x, qb0.x, rB); rB = fmaf(lo.y, qb0.y, rB);
          rB = fmaf(lo.z, qb0.z, rB); rB = fmaf(lo.w, qb0.w, rB);
          rB = fmaf(hi.x, qb1.x, rB); rB = fmaf(hi.y, qb1.y, rB);
          rB = fmaf(hi.z, qb1.z, rB); rB = fmaf(hi.w, qb1.w, rB);
        }
      }
      float f0, f1, f2;
      act012(net, zA, f0, f1, f2);
      bufA[0][t] = f0; act1[0][t] = f1; d2a[0][t] = f2; rbuf[0][t] = rA;
      act012(net, zB, f0, f1, f2);
      bufA[1][t] = f0; act1[1][t] = f1; d2a[1][t] = f2; rbuf[1][t] = rB;
    }
    __syncthreads();

    // ---- P2: z2 (both) via shared bf16 W2 column loads ----
    {
      float b2t = b2[t];
      float zA0 = b2t, zA1 = 0.f, zB0 = b2t, zB1 = 0.f;
      const short* wcol = w4 + t * Hh;
      for (int kb = 0; kb < 32; ++kb) {
        bf8_t wv = *(const bf8_t*)&wcol[kb * 8];
        f4_t lo, hi; bf8_to_f(wv, lo, hi);
        float4 hA0 = *(const float4*)&bufA[0][kb * 8];
        float4 hA1 = *(const float4*)&bufA[0][kb * 8 + 4];
        float4 hB0 = *(const float4*)&bufA[1][kb * 8];
        float4 hB1 = *(const float4*)&bufA[1][kb * 8 + 4];
        zA0 = fmaf(lo.x, hA0.x, zA0); zA0 = fmaf(lo.y, hA0.y, zA0);
        zA0 = fmaf(lo.z, hA0.z, zA0); zA0 = fmaf(lo.w, hA0.w, zA0);
        zA1 = fmaf(hi.x, hA1.x, zA1); zA1 = fmaf(hi.y, hA1.y, zA1);
        zA1 = fmaf(hi.z, hA1.z, zA1); zA1 = fmaf(hi.w, hA1.w, zA1);
        zB0 = fmaf(lo.x, hB0.x, zB0); zB0 = fmaf(lo.y, hB0.y, zB0);
        zB0 = fmaf(lo.z, hB0.z, zB0); zB0 = fmaf(lo.w, hB0.w, zB0);
        zB1 = fmaf(hi.x, hB1.x, zB1); zB1 = fmaf(hi.y, hB1.y, zB1);
        zB1 = fmaf(hi.z, hB1.z, zB1); zB1 = fmaf(hi.w, hB1.w, zB1);
      }
      float w3t = W3[t];
      float g1, g2;
      act12(net, zA0 + zA1, g1, g2);
      s2[0][t] = w3t * g1; bco[0][t] = w3t * g2;
      act12(net, zB0 + zB1, g1, g2);
      s2[1][t] = w3t * g1; bco[1][t] = w3t * g2;
    }
    __syncthreads();

    // ---- P3: v (both) via fp32 W2 rows (contiguous float4) ----
    {
      const float* wrow = W2 + t * Hh;
      float vA0 = 0.f, vA1 = 0.f, vB0 = 0.f, vB1 = 0.f;
      for (int j = 0; j < Hh; j += 8) {
        float4 w0 = *(const float4*)&wrow[j];
        float4 w1 = *(const float4*)&wrow[j + 4];
        float4 sA0 = *(const float4*)&s2[0][j];
        float4 sA1 = *(const float4*)&s2[0][j + 4];
        float4 sB0 = *(const float4*)&s2[1][j];
        float4 sB1 = *(const float4*)&s2[1][j + 4];
        vA0 = fmaf(w0.x, sA0.x, vA0); vA0 = fmaf(w0.y, sA0.y, vA0);
        vA0 = fmaf(w0.z, sA0.z, vA0); vA0 = fmaf(w0.w, sA0.w, vA0);
        vA1 = fmaf(w1.x, sA1.x, vA1); vA1 = fmaf(w1.y, sA1.y, vA1);
        vA1 = fmaf(w1.z, sA1.z, vA1); vA1 = fmaf(w1.w, sA1.w, vA1);
        vB0 = fmaf(w0.x, sB0.x, vB0); vB0 = fmaf(w0.y, sB0.y, vB0);
        vB0 = fmaf(w0.z, sB0.z, vB0); vB0 = fmaf(w0.w, sB0.w, vB0);
        vB1 = fmaf(w1.x, sB1.x, vB1); vB1 = fmaf(w1.y, sB1.y, vB1);
        vB1 = fmaf(w1.z, sB1.z, vB1); vB1 = fmaf(w1.w, sB1.w, vB1);
      }
      float vA = vA0 + vA1, vB = vB0 + vB1;
      uarr[0][t] = act1[0][t] * vA;  aarr[0][t] = d2a[0][t] * vA;
      bufB[0][t] = act1[0][t] * rbuf[0][t];
      uarr[1][t] = act1[1][t] * vB;  aarr[1][t] = d2a[1][t] * vB;
      bufB[1][t] = act1[1][t] * rbuf[1][t];
    }
    __syncthreads();

    // ---- P4: twv (both) ; jac/Bq1 partials (both) ; T-GEMM (both, MFMA) ----
    {
      float tA0 = 0.f, tA1 = 0.f, tB0 = 0.f, tB1 = 0.f;
      const short* wcol = w4 + t * Hh;
      for (int kb = 0; kb < 32; ++kb) {
        bf8_t wv = *(const bf8_t*)&wcol[kb * 8];
        f4_t lo, hi; bf8_to_f(wv, lo, hi);
        float4 uA0 = *(const float4*)&bufB[0][kb * 8];
        float4 uA1 = *(const float4*)&bufB[0][kb * 8 + 4];
        float4 uB0 = *(const float4*)&bufB[1][kb * 8];
        float4 uB1 = *(const float4*)&bufB[1][kb * 8 + 4];
        tA0 = fmaf(lo.x, uA0.x, tA0); tA0 = fmaf(lo.y, uA0.y, tA0);
        tA0 = fmaf(lo.z, uA0.z, tA0); tA0 = fmaf(lo.w, uA0.w, tA0);
        tA1 = fmaf(hi.x, uA1.x, tA1); tA1 = fmaf(hi.y, uA1.y, tA1);
        tA1 = fmaf(hi.z, uA1.z, tA1); tA1 = fmaf(hi.w, uA1.w, tA1);
        tB0 = fmaf(lo.x, uB0.x, tB0); tB0 = fmaf(lo.y, uB0.y, tB0);
        tB0 = fmaf(lo.z, uB0.z, tB0); tB0 = fmaf(lo.w, uB0.w, tB0);
        tB1 = fmaf(hi.x, uB1.x, tB1); tB1 = fmaf(hi.y, uB1.y, tB1);
        tB1 = fmaf(hi.z, uB1.z, tB1); tB1 = fmaf(hi.w, uB1.w, tB1);
      }
      s2[0][t] = bco[0][t] * (tA0 + tA1);   // twv
      s2[1][t] = bco[1][t] * (tB0 + tB1);
    }
    {
      int i = t & 31, seg = t >> 5;
      const float* wt = W1 + i * Hh + seg * 32;
      const float* wb = W1 + (Nn + i) * Hh + seg * 32;
      float jaA = 0.f, bqA = 0.f, jaB = 0.f, bqB = 0.f;
      #pragma unroll
      for (int k2 = 0; k2 < 32; k2 += 4) {
        int kk = seg * 32 + k2;
        float4 wtv = *(const float4*)&wt[k2];
        float4 wbv = *(const float4*)&wb[k2];
        float4 uA = *(const float4*)&uarr[0][kk];
        float4 uB = *(const float4*)&uarr[1][kk];
        float4 aA = *(const float4*)&aarr[0][kk];
        float4 aB = *(const float4*)&aarr[1][kk];
        float4 rA = *(const float4*)&rbuf[0][kk];
        float4 rB = *(const float4*)&rbuf[1][kk];
        jaA = fmaf(wtv.x, uA.x, jaA); jaA = fmaf(wtv.y, uA.y, jaA);
        jaA = fmaf(wtv.z, uA.z, jaA); jaA = fmaf(wtv.w, uA.w, jaA);
        jaB = fmaf(wtv.x, uB.x, jaB); jaB = fmaf(wtv.y, uB.y, jaB);
        jaB = fmaf(wtv.z, uB.z, jaB); jaB = fmaf(wtv.w, uB.w, jaB);
        bqA = fmaf(wbv.x, aA.x * rA.x, bqA); bqA = fmaf(wbv.y, aA.y * rA.y, bqA);
        bqA = fmaf(wbv.z, aA.z * rA.z, bqA); bqA = fmaf(wbv.w, aA.w * rA.w, bqA);
        bqB = fmaf(wbv.x, aB.x * rB.x, bqB); bqB = fmaf(wbv.y, aB.y * rB.y, bqB);
        bqB = fmaf(wbv.z, aB.z * rB.z, bqB); bqB = fmaf(wbv.w, aB.w * rB.w, bqB);
      }
      bufA[0][t] = jaA; d2a[0][t] = bqA;   // repurpose
      bufA[1][t] = jaB; d2a[1][t] = bqB;
    }
    // T-GEMM: T[m][j] = sum_k (W1bot[m,k]*act1[k]) * W2[k,j]
    #pragma unroll
    for (int half = 0; half < 2; ++half) {
      f4_t tacc[2][2][2];
      #pragma unroll
      for (int sm = 0; sm < 2; ++sm)
        #pragma unroll
        for (int a = 0; a < 2; ++a)
          #pragma unroll
          for (int b = 0; b < 2; ++b) tacc[sm][a][b] = (f4_t){0.f, 0.f, 0.f, 0.f};
      for (int kb = 0; kb < 8; ++kb) {
        int kbase = kb * 32 + q * 8;
        f4_t aA0 = *(const f4_t*)&act1[0][kbase];
        f4_t aA1 = *(const f4_t*)&act1[0][kbase + 4];
        f4_t aB0 = *(const f4_t*)&act1[1][kbase];
        f4_t aB1 = *(const f4_t*)&act1[1][kbase + 4];
        bf8_t afrag[2][2];
        #pragma unroll
        for (int mt = 0; mt < 2; ++mt) {
          bf8_t w8 = *(const bf8_t*)&ws1[((((net * 2 + mt) * 8) + kb) << 9) + lane * 8];
          f4_t lo, hi; bf8_to_f(w8, lo, hi);
          afrag[0][mt] = pack8(lo * aA0, hi * aA1);
          afrag[1][mt] = pack8(lo * aB0, hi * aB1);
        }
        #pragma unroll
        for (int j = 0; j < 2; ++j) {
          int nt = w + (half * 2 + j) * 4;
          bf8_t bf = *(const bf8_t*)&w4[(nt * 16 + ln16) * Hh + kbase];
          #pragma unroll
          for (int sm = 0; sm < 2; ++sm) {
            tacc[sm][0][j] = __builtin_amdgcn_mfma_f32_16x16x32_bf16(afrag[sm][0], bf, tacc[sm][0][j], 0, 0, 0);
            tacc[sm][1][j] = __builtin_amdgcn_mfma_f32_16x16x32_bf16(afrag[sm][1], bf, tacc[sm][1][j], 0, 0, 0);
          }
        }
      }
      #pragma unroll
      for (int sm = 0; sm < 2; ++sm)
        #pragma unroll
        for (int mt = 0; mt < 2; ++mt)
          #pragma unroll
          for (int j = 0; j < 2; ++j) {
            int nt = w + (half * 2 + j) * 4;
            int col = nt * 16 + ln16;
            int rowb = mt * 16 + q * 4;
            Tp[sm][(rowb + 0) * TS + col] = f2bf(tacc[sm][mt][j][0]);
            Tp[sm][(rowb + 1) * TS + col] = f2bf(tacc[sm][mt][j][1]);
            Tp[sm][(rowb + 2) * TS + col] = f2bf(tacc[sm][mt][j][2]);
            Tp[sm][(rowb + 3) * TS + col] = f2bf(tacc[sm][mt][j][3]);
          }
    }
    __syncthreads();

    // ---- P5: reduce jac/Bq1 ; Bq2 partials ; SYRK (both, MFMA) ----
    if (t < 64) {
      int smp = t >> 5, r = t & 31;
      float ja = 0.f, bq = 0.f;
      #pragma unroll
      for (int g = 0; g < 8; ++g) { ja += bufA[smp][g * 32 + r]; bq += d2a[smp][g * 32 + r]; }
      jacv[smp][r] += ja; Bqv[smp][r] += bq;
    }
    {
      int p = t & 31, seg = t >> 5;
      #pragma unroll
      for (int sm = 0; sm < 2; ++sm) {
        float acc = 0.f;
        #pragma unroll
        for (int j4 = 0; j4 < 4; ++j4) {
          int jb = seg * 32 + j4 * 8;
          bf8_t t8 = *(const bf8_t*)&Tp[sm][p * TS + jb];
          f4_t lo, hi; bf8_to_f(t8, lo, hi);
          float4 sv0 = *(const float4*)&s2[sm][jb];
          float4 sv1 = *(const float4*)&s2[sm][jb + 4];
          acc = fmaf(lo.x, sv0.x, acc); acc = fmaf(lo.y, sv0.y, acc);
          acc = fmaf(lo.z, sv0.z, acc); acc = fmaf(lo.w, sv0.w, acc);
          acc = fmaf(hi.x, sv1.x, acc); acc = fmaf(hi.y, sv1.y, acc);
          acc = fmaf(hi.z, sv1.z, acc); acc = fmaf(hi.w, sv1.w, acc);
        }
        uarr[sm][t] = acc;   // Bq2 partial
      }
    }
    // SYRK W-term: A += (W1bot*aarr) W1bot^T
    for (int kb = 0; kb < 8; ++kb) {
      int kbase = kb * 32 + q * 8;
      bf8_t am8 = *(const bf8_t*)&ws1[((((net * 2 + mtS) * 8) + kb) << 9) + lane * 8];
      bf8_t bn8 = *(const bf8_t*)&ws1[((((net * 2 + ntS) * 8) + kb) << 9) + lane * 8];
      f4_t lo, hi; bf8_to_f(am8, lo, hi);
      #pragma unroll
      for (int sm = 0; sm < 2; ++sm) {
        f4_t aa0 = *(const f4_t*)&aarr[sm][kbase];
        f4_t aa1 = *(const f4_t*)&aarr[sm][kbase + 4];
        bf8_t afr = pack8(lo * aa0, hi * aa1);
        sacc[sm] = __builtin_amdgcn_mfma_f32_16x16x32_bf16(afr, bn8, sacc[sm], 0, 0, 0);
      }
    }
    // SYRK T-term: A += (T*bco) T^T
    for (int jb = 0; jb < 8; ++jb) {
      int jbase = jb * 32 + q * 8;
      #pragma unroll
      for (int sm = 0; sm < 2; ++sm) {
        f4_t bc0 = *(const f4_t*)&bco[sm][jbase];
        f4_t bc1 = *(const f4_t*)&bco[sm][jbase + 4];
        bf8_t ta = *(const bf8_t*)&Tp[sm][(mtS * 16 + ln16) * TS + jbase];
        bf8_t tb = *(const bf8_t*)&Tp[sm][(ntS * 16 + ln16) * TS + jbase];
        bf8_t afr;
        afr[0] = f2bf(bf2f(ta[0]) * bc0.x);
        afr[1] = f2bf(bf2f(ta[1]) * bc0.y);
        afr[2] = f2bf(bf2f(ta[2]) * bc0.z);
        afr[3] = f2bf(bf2f(ta[3]) * bc0.w);
        afr[4] = f2bf(bf2f(ta[4]) * bc1.x);
        afr[5] = f2bf(bf2f(ta[5]) * bc1.y);
        afr[6] = f2bf(bf2f(ta[6]) * bc1.z);
        afr[7] = f2bf(bf2f(ta[7]) * bc1.w);
        sacc[sm] = __builtin_amdgcn_mfma_f32_16x16x32_bf16(afr, tb, sacc[sm], 0, 0, 0);
      }
    }
    __syncthreads();
  }

  // ---- final Bq2 reduce ----
  if (t < 64) {
    int smp = t >> 5, r = t & 31;
    float bq = 0.f;
    #pragma unroll
    for (int g = 0; g < 8; ++g) bq += uarr[smp][g * 32 + r];
    Bqv[smp][r] += bq;
  }
  // ---- SYRK tiles -> Aug ----
  {
    int col = ntS * 16 + ln16;
    int rowb = mtS * 16 + q * 4;
    #pragma unroll
    for (int sm = 0; sm < 2; ++sm) {
      Aug[sm][rowb + 0][col] = sacc[sm][0];
      Aug[sm][rowb + 1][col] = sacc[sm][1];
      Aug[sm][rowb + 2][col] = sacc[sm][2];
      Aug[sm][rowb + 3][col] = sacc[sm][3];
    }
  }
  __syncthreads();
  if (t < 64) {
    int smp = t >> 5, r = t & 31;
    Aug[smp][r][r] += 2.0f;
    Aug[smp][r][Nn] = jacv[smp][r] - Bqv[smp][r];
  }
  __syncthreads();

  // ---- register Gauss-Jordan, no pivot (A = 2I + small): wave0->s0, wave1->s1 ----
  if (w < 2 && (lane) < 32) {
    int smp = w, r = lane;
    float a[Nn + 1];
    #pragma unroll
    for (int c = 0; c <= Nn; ++c) a[c] = Aug[smp][r][c];
    float mydiag = 1.f;
    #pragma unroll
    for (int st = 0; st < Nn; ++st) {
      float pd = __shfl(a[st], st, 64);
      mydiag = (r == st) ? pd : mydiag;
      float f = a[st] / pd;
      bool self = (r == st);
      #pragma unroll
      for (int c = st + 1; c <= Nn; ++c) {
        float pc = __shfl(a[c], st, 64);
        if (!self) a[c] = fmaf(-f, pc, a[c]);
      }
    }
    out[(s0 + smp) * Dd + r] = xr[smp][Nn + r];          // qdot
    out[(s0 + smp) * Dd + Nn + r] = a[Nn] / mydiag;      // qdd
  }
}

extern "C" void kernel_launch(void* const* d_in, const int* in_sizes, int n_in,
                              void* d_out, int out_size, void* d_ws, size_t ws_size,
                              hipStream_t stream) {
  const float* x   = (const float*)d_in[0];
  const float* mW1 = (const float*)d_in[1];
  const float* mb1 = (const float*)d_in[2];
  const float* mW2 = (const float*)d_in[3];
  const float* mb2 = (const float*)d_in[4];
  const float* mW3 = (const float*)d_in[5];
  const float* qW1 = (const float*)d_in[6];
  const float* qb1 = (const float*)d_in[7];
  const float* qW2 = (const float*)d_in[8];
  const float* qb2 = (const float*)d_in[9];
  const float* qW3 = (const float*)d_in[10];

  short* ws4 = (short*)d_ws;                          // 2 x 65536 bf16 = 256 KB
  short* ws1 = (short*)((char*)d_ws + 262144);        // 2 x 8192 bf16  = 32 KB
  short* ws6 = (short*)((char*)d_ws + 294912);        // 2 x 16384 bf16 = 64 KB

  pack_kernel<<<dim3(704), dim3(256), 0, stream>>>(mW1, mW2, qW1, qW2, ws4, ws1, ws6);

  const int B = in_sizes[0] / Dd;   // 4096
  lnn_kernel<<<dim3(B / 2), dim3(256), 0, stream>>>(
      x, mW1, mb1, mW2, mb2, mW3, qW1, qb1, qW2, qb2, qW3, ws4, ws1, ws6, (float*)d_out);
}

// Round 6
// 395.340 us; speedup vs baseline: 5.8573x; 1.2030x over previous
//
#include <hip/hip_runtime.h>
#include <math.h>

#define Hh 256
#define Dd 64
#define Nn 32
#define MS 272   // megaA stride (shorts): 544 B/row -> uniform 8-lane/bank b128 reads
#define TS 264   // Tp stride (shorts)
#define AS 33    // Aug stride (floats): 32 cols A + 1 rhs

typedef __attribute__((ext_vector_type(8))) short bf8_t;
typedef __attribute__((ext_vector_type(4))) float f4_t;

__device__ __forceinline__ short f2bf(float f) {
  union { float f; unsigned u; } v; v.f = f;
  unsigned r = v.u + 0x7FFFu + ((v.u >> 16) & 1u);
  return (short)(r >> 16);
}
__device__ __forceinline__ float bf2f(short s) {
  union { unsigned u; float f; } v;
  v.u = ((unsigned)(unsigned short)s) << 16;
  return v.f;
}
__device__ __forceinline__ bf8_t pack8(f4_t lo, f4_t hi) {
  bf8_t r;
  r[0] = f2bf(lo.x); r[1] = f2bf(lo.y); r[2] = f2bf(lo.z); r[3] = f2bf(lo.w);
  r[4] = f2bf(hi.x); r[5] = f2bf(hi.y); r[6] = f2bf(hi.z); r[7] = f2bf(hi.w);
  return r;
}
__device__ __forceinline__ void bf8_to_f(bf8_t v, f4_t& lo, f4_t& hi) {
  lo.x = bf2f(v[0]); lo.y = bf2f(v[1]); lo.z = bf2f(v[2]); lo.w = bf2f(v[3]);
  hi.x = bf2f(v[4]); hi.y = bf2f(v[5]); hi.z = bf2f(v[6]); hi.w = bf2f(v[7]);
}
__device__ __forceinline__ void act012(int net, float z, float& f0, float& f1, float& f2) {
  if (net == 0) {
    float e = __expf(-z);
    float sg = 1.f / (1.f + e);
    f0 = (z > 20.f) ? z : __logf(1.f + __expf(z));
    f1 = sg; f2 = sg * (1.f - sg);
  } else {
    float az = fabsf(z);
    float e = __expf(-az);
    float th = (1.f - e) / (1.f + e);
    th = (z < 0.f) ? -th : th;
    float sech2 = 1.f - th * th;
    f0 = z * th;
    f1 = th + 0.5f * z * sech2;
    f2 = sech2 * (1.f - 0.5f * z * th);
  }
}
__device__ __forceinline__ void act12(int net, float z, float& g1, float& g2) {
  if (net == 0) {
    float e = __expf(-z);
    float sg = 1.f / (1.f + e);
    g1 = sg; g2 = sg * (1.f - sg);
  } else {
    float az = fabsf(z);
    float e = __expf(-az);
    float th = (1.f - e) / (1.f + e);
    th = (z < 0.f) ? -th : th;
    float sech2 = 1.f - th * th;
    g1 = th + 0.5f * z * sech2;
    g2 = sech2 * (1.f - 0.5f * z * th);
  }
}

// ---- pre-pack ----
// ws4[net*65536 + c*256 + k]             = bf16(W2[k][c])   (W2 n-major; B for k-reduction)
// ws5[net*65536 + k*256 + j]             = bf16(W2[k][j])   (W2 row-major; B for j-reduction)
// ws1[((net*2+mt)*8+kb)*512 + lane*8+jj] = bf16(W1[32+mt*16+(lane&15)][kb*32+(lane>>4)*8+jj])
// ws6[net*16384 + t*64 + i]              = bf16(W1[i][t])   (W1 columns contiguous)
__global__ void pack_kernel(const float* __restrict__ mW1, const float* __restrict__ mW2,
                            const float* __restrict__ qW1, const float* __restrict__ qW2,
                            short* __restrict__ ws4, short* __restrict__ ws5,
                            short* __restrict__ ws1, short* __restrict__ ws6) {
  int id = blockIdx.x * 256 + threadIdx.x;
  if (id < 131072) {
    int net = id >> 16;
    const float* W2 = net ? qW2 : mW2;
    int c = (id >> 8) & 255, k = id & 255;
    ws4[id] = f2bf(W2[k * Hh + c]);
  } else if (id < 262144) {
    int id2 = id - 131072;
    int net = id2 >> 16;
    const float* W2 = net ? qW2 : mW2;
    int k = (id2 >> 8) & 255, j = id2 & 255;
    ws5[id2] = f2bf(W2[k * Hh + j]);
  } else if (id < 278528) {
    int id2 = id - 262144;
    int net = id2 >> 13, r = id2 & 8191;
    const float* W1 = net ? qW1 : mW1;
    int mt = r >> 12, kb = (r >> 9) & 7, lane = (r >> 3) & 63, jj = r & 7;
    int m = Nn + mt * 16 + (lane & 15);
    int k = kb * 32 + (lane >> 4) * 8 + jj;
    ws1[id2] = f2bf(W1[m * Hh + k]);
  } else if (id < 311296) {
    int id3 = id - 278528;
    int net = id3 >> 14, r = id3 & 16383;
    const float* W1 = net ? qW1 : mW1;
    int tc = r >> 6, i = r & 63;
    ws6[id3] = f2bf(W1[i * Hh + tc]);
  }
}

__global__ __launch_bounds__(256, 2) void lnn_kernel(
    const float* __restrict__ x,
    const float* __restrict__ mW1, const float* __restrict__ mb1,
    const float* __restrict__ mW2, const float* __restrict__ mb2,
    const float* __restrict__ mW3,
    const float* __restrict__ qW1, const float* __restrict__ qb1,
    const float* __restrict__ qW2, const float* __restrict__ qb2,
    const float* __restrict__ qW3,
    const short* __restrict__ ws4, const short* __restrict__ ws5,
    const short* __restrict__ ws1, const short* __restrict__ ws6,
    float* __restrict__ out)
{
  const int t = threadIdx.x;
  const int w = t >> 6, lane = t & 63, q = lane >> 4, ln16 = lane & 15;
  const int s0 = blockIdx.x * 2;

  // megaA: rows 0-31 = staged GEMM A-tiles (T-rows / SYRK-W rows),
  //        rows 32-47 = vec-tile rows, rows 48-63 = SYRK-W s1 rows, then Aug alias.
  __shared__ __align__(16) short megaA[64 * MS];      // 34,816 B
  __shared__ __align__(16) short Tp[Nn * TS];         // 16,896 B (one sample at a time)
  __shared__ __align__(16) float xr[2][Dd];
  __shared__ __align__(16) float act1[2][Hh], d2a[2][Hh], rbuf[2][Hh], bco[2][Hh];
  __shared__ __align__(16) float buf1[2][Hh];         // z2pre -> v
  __shared__ __align__(16) float buf2[2][Hh];         // t -> twv
  __shared__ float jacv[2][Nn], Bqv[2][Nn];
  float* AugF = (float*)&megaA[48 * MS];              // alias, 2*32*33*4 = 8448 B <= 8704 B

  if (t < 128) ((float*)xr)[t] = x[s0 * Dd + t];
  if (t < 64) { jacv[t >> 5][t & 31] = 0.f; Bqv[t >> 5][t & 31] = 0.f; }
  __syncthreads();

  f4_t sacc[2];
  sacc[0] = (f4_t){0.f, 0.f, 0.f, 0.f};
  sacc[1] = (f4_t){0.f, 0.f, 0.f, 0.f};
  const int mtS = w >> 1, ntS = w & 1;
  const int rg = w * 8 + (lane >> 3);   // row for shuffle-reduced GEMVs (0..31)
  const int kc = (lane & 7) * 32;       // k-chunk for shuffle-reduced GEMVs

  for (int net = 0; net < 2; ++net) {
    const float* W1 = net ? qW1 : mW1;
    const float* b1 = net ? qb1 : mb1;
    const float* b2 = net ? qb2 : mb2;
    const float* W3 = net ? qW3 : mW3;
    const short* w4 = ws4 + net * 65536;
    const short* w5 = ws5 + net * 65536;
    const short* w1f = ws1 + net * 8192;
    const short* w6 = ws6 + net * 16384 + t * 64;

    // ================= P1a: z1 + rbuf (both samples); vec rows; zero pads =================
    {
      float b1t = b1[t];
      float zA = b1t, zB = b1t, rA = 0.f, rB = 0.f;
      #pragma unroll
      for (int ib = 0; ib < 8; ++ib) {
        bf8_t w8 = *(const bf8_t*)&w6[ib * 8];
        f4_t lo, hi; bf8_to_f(w8, lo, hi);
        float4 xa0 = *(const float4*)&xr[0][ib * 8];
        float4 xa1 = *(const float4*)&xr[0][ib * 8 + 4];
        float4 xb0 = *(const float4*)&xr[1][ib * 8];
        float4 xb1 = *(const float4*)&xr[1][ib * 8 + 4];
        zA = fmaf(lo.x, xa0.x, zA); zA = fmaf(lo.y, xa0.y, zA);
        zA = fmaf(lo.z, xa0.z, zA); zA = fmaf(lo.w, xa0.w, zA);
        zA = fmaf(hi.x, xa1.x, zA); zA = fmaf(hi.y, xa1.y, zA);
        zA = fmaf(hi.z, xa1.z, zA); zA = fmaf(hi.w, xa1.w, zA);
        zB = fmaf(lo.x, xb0.x, zB); zB = fmaf(lo.y, xb0.y, zB);
        zB = fmaf(lo.z, xb0.z, zB); zB = fmaf(lo.w, xb0.w, zB);
        zB = fmaf(hi.x, xb1.x, zB); zB = fmaf(hi.y, xb1.y, zB);
        zB = fmaf(hi.z, xb1.z, zB); zB = fmaf(hi.w, xb1.w, zB);
        if (ib < 4) {   // W1 rows 0..31 also hit qdot for rbuf
          float4 qa0 = *(const float4*)&xr[0][Nn + ib * 8];
          float4 qa1 = *(const float4*)&xr[0][Nn + ib * 8 + 4];
          float4 qb0 = *(const float4*)&xr[1][Nn + ib * 8];
          float4 qb1 = *(const float4*)&xr[1][Nn + ib * 8 + 4];
          rA = fmaf(lo.x, qa0.x, rA); rA = fmaf(lo.y, qa0.y, rA);
          rA = fmaf(lo.z, qa0.z, rA); rA = fmaf(lo.w, qa0.w, rA);
          rA = fmaf(hi.x, qa1.x, rA); rA = fmaf(hi.y, qa1.y, rA);
          rA = fmaf(hi.z, qa1.z, rA); rA = fmaf(hi.w, qa1.w, rA);
          rB = fmaf(lo.x, qb0.x, rB); rB = fmaf(lo.y, qb0.y, rB);
          rB = fmaf(lo.z, qb0.z, rB); rB = fmaf(lo.w, qb0.w, rB);
          rB = fmaf(hi.x, qb1.x, rB); rB = fmaf(hi.y, qb1.y, rB);
          rB = fmaf(hi.z, qb1.z, rB); rB = fmaf(hi.w, qb1.w, rB);
        }
      }
      float f0, f1, f2;
      act012(net, zA, f0, f1, f2);
      act1[0][t] = f1; d2a[0][t] = f2; rbuf[0][t] = rA;
      megaA[32 * MS + t] = f2bf(f0);            // h1_s0
      megaA[34 * MS + t] = f2bf(f1 * rA);       // u_s0 = act1*rbuf
      act012(net, zB, f0, f1, f2);
      act1[1][t] = f1; d2a[1][t] = f2; rbuf[1][t] = rB;
      megaA[33 * MS + t] = f2bf(f0);            // h1_s1
      megaA[35 * MS + t] = f2bf(f1 * rB);       // u_s1
      #pragma unroll
      for (int r = 36; r < 48; ++r) megaA[r * MS + t] = 0;
    }
    __syncthreads();

    // ================= P1b: stage T_s0 A-rows = act1_s0[k] * W1bot[m][k] =================
    {
      int m = t >> 3, kb = t & 7;
      int base = ((m >> 4) * 8 + kb) * 512 + (m & 15) * 8;
      #pragma unroll
      for (int q2 = 0; q2 < 4; ++q2) {
        bf8_t w8 = *(const bf8_t*)&w1f[base + q2 * 128];
        f4_t lo, hi; bf8_to_f(w8, lo, hi);
        int k0 = kb * 32 + q2 * 8;
        f4_t a0 = *(const f4_t*)&act1[0][k0];
        f4_t a1 = *(const f4_t*)&act1[0][k0 + 4];
        *(bf8_t*)&megaA[m * MS + k0] = pack8(lo * a0, hi * a1);
      }
    }
    __syncthreads();

    // ================= pass1 GEMM: [T_s0 | h1/u vecs] x W2(n-major) =================
    {
      f4_t acc0[4], acc1[4], acc2[4];
      #pragma unroll
      for (int j = 0; j < 4; ++j) {
        acc0[j] = (f4_t){0.f,0.f,0.f,0.f};
        acc1[j] = (f4_t){0.f,0.f,0.f,0.f};
        acc2[j] = (f4_t){0.f,0.f,0.f,0.f};
      }
      for (int kb = 0; kb < 8; ++kb) {
        int kk = kb * 32 + q * 8;
        bf8_t av0 = *(const bf8_t*)&megaA[(ln16) * MS + kk];
        bf8_t av1 = *(const bf8_t*)&megaA[(16 + ln16) * MS + kk];
        bf8_t av2 = *(const bf8_t*)&megaA[(32 + ln16) * MS + kk];
        #pragma unroll
        for (int j = 0; j < 4; ++j) {
          bf8_t bv = *(const bf8_t*)&w4[((w * 4 + j) * 16 + ln16) * Hh + kk];
          acc0[j] = __builtin_amdgcn_mfma_f32_16x16x32_bf16(av0, bv, acc0[j], 0, 0, 0);
          acc1[j] = __builtin_amdgcn_mfma_f32_16x16x32_bf16(av1, bv, acc1[j], 0, 0, 0);
          acc2[j] = __builtin_amdgcn_mfma_f32_16x16x32_bf16(av2, bv, acc2[j], 0, 0, 0);
        }
      }
      #pragma unroll
      for (int j = 0; j < 4; ++j) {
        int col = (w * 4 + j) * 16 + ln16;
        int r0 = q * 4;
        Tp[(r0 + 0) * TS + col] = f2bf(acc0[j][0]);
        Tp[(r0 + 1) * TS + col] = f2bf(acc0[j][1]);
        Tp[(r0 + 2) * TS + col] = f2bf(acc0[j][2]);
        Tp[(r0 + 3) * TS + col] = f2bf(acc0[j][3]);
        Tp[(16 + r0 + 0) * TS + col] = f2bf(acc1[j][0]);
        Tp[(16 + r0 + 1) * TS + col] = f2bf(acc1[j][1]);
        Tp[(16 + r0 + 2) * TS + col] = f2bf(acc1[j][2]);
        Tp[(16 + r0 + 3) * TS + col] = f2bf(acc1[j][3]);
        if (q == 0) {
          buf1[0][col] = acc2[j][0];   // z2pre_s0
          buf1[1][col] = acc2[j][1];   // z2pre_s1
          buf2[0][col] = acc2[j][2];   // t_s0
          buf2[1][col] = acc2[j][3];   // t_s1
        }
      }
    }
    __syncthreads();

    // ================= VALU2a: s2/bco/twv; stage T_s1 rows + s2 vec rows =================
    {
      float w3t = W3[t];
      float b2t = b2[t];
      float g1, g2;
      act12(net, buf1[0][t] + b2t, g1, g2);
      megaA[32 * MS + t] = f2bf(w3t * g1);   // s2_s0
      bco[0][t] = w3t * g2;
      buf2[0][t] = (w3t * g2) * buf2[0][t];  // twv_s0
      act12(net, buf1[1][t] + b2t, g1, g2);
      megaA[33 * MS + t] = f2bf(w3t * g1);   // s2_s1
      bco[1][t] = w3t * g2;
      buf2[1][t] = (w3t * g2) * buf2[1][t];  // twv_s1
      megaA[34 * MS + t] = 0; megaA[35 * MS + t] = 0;
    }
    {
      int m = t >> 3, kb = t & 7;
      int base = ((m >> 4) * 8 + kb) * 512 + (m & 15) * 8;
      #pragma unroll
      for (int q2 = 0; q2 < 4; ++q2) {
        bf8_t w8 = *(const bf8_t*)&w1f[base + q2 * 128];
        f4_t lo, hi; bf8_to_f(w8, lo, hi);
        int k0 = kb * 32 + q2 * 8;
        f4_t a0 = *(const f4_t*)&act1[1][k0];
        f4_t a1 = *(const f4_t*)&act1[1][k0 + 4];
        *(bf8_t*)&megaA[m * MS + k0] = pack8(lo * a0, hi * a1);
      }
    }
    __syncthreads();

    // ================= VALU2b: SYRK-T(s0) + Bq2(s0) =================
    for (int jb = 0; jb < 8; ++jb) {
      int jbase = jb * 32 + q * 8;
      f4_t bc0 = *(const f4_t*)&bco[0][jbase];
      f4_t bc1 = *(const f4_t*)&bco[0][jbase + 4];
      bf8_t ta = *(const bf8_t*)&Tp[(mtS * 16 + ln16) * TS + jbase];
      bf8_t tb = *(const bf8_t*)&Tp[(ntS * 16 + ln16) * TS + jbase];
      f4_t lo, hi; bf8_to_f(ta, lo, hi);
      bf8_t afr = pack8(lo * bc0, hi * bc1);
      sacc[0] = __builtin_amdgcn_mfma_f32_16x16x32_bf16(afr, tb, sacc[0], 0, 0, 0);
    }
    {
      float a = 0.f;
      #pragma unroll
      for (int j4 = 0; j4 < 4; ++j4) {
        int jb = kc + j4 * 8;
        bf8_t t8 = *(const bf8_t*)&Tp[rg * TS + jb];
        f4_t lo, hi; bf8_to_f(t8, lo, hi);
        float4 tv0 = *(const float4*)&buf2[0][jb];
        float4 tv1 = *(const float4*)&buf2[0][jb + 4];
        a = fmaf(lo.x, tv0.x, a); a = fmaf(lo.y, tv0.y, a);
        a = fmaf(lo.z, tv0.z, a); a = fmaf(lo.w, tv0.w, a);
        a = fmaf(hi.x, tv1.x, a); a = fmaf(hi.y, tv1.y, a);
        a = fmaf(hi.z, tv1.z, a); a = fmaf(hi.w, tv1.w, a);
      }
      a += __shfl_xor(a, 1, 64);
      a += __shfl_xor(a, 2, 64);
      a += __shfl_xor(a, 4, 64);
      if ((lane & 7) == 0) Bqv[0][rg] += a;
    }
    __syncthreads();

    // ================= pass2 GEMM: [T_s1 | s2 vecs] ; vec tile vs W2(row-major) =================
    {
      f4_t acc0[4], acc1[4], acc2[4];
      #pragma unroll
      for (int j = 0; j < 4; ++j) {
        acc0[j] = (f4_t){0.f,0.f,0.f,0.f};
        acc1[j] = (f4_t){0.f,0.f,0.f,0.f};
        acc2[j] = (f4_t){0.f,0.f,0.f,0.f};
      }
      for (int kb = 0; kb < 8; ++kb) {
        int kk = kb * 32 + q * 8;
        bf8_t av0 = *(const bf8_t*)&megaA[(ln16) * MS + kk];
        bf8_t av1 = *(const bf8_t*)&megaA[(16 + ln16) * MS + kk];
        bf8_t av2 = *(const bf8_t*)&megaA[(32 + ln16) * MS + kk];
        #pragma unroll
        for (int j = 0; j < 4; ++j) {
          bf8_t bv4 = *(const bf8_t*)&w4[((w * 4 + j) * 16 + ln16) * Hh + kk];
          bf8_t bv5 = *(const bf8_t*)&w5[((w * 4 + j) * 16 + ln16) * Hh + kk];
          acc0[j] = __builtin_amdgcn_mfma_f32_16x16x32_bf16(av0, bv4, acc0[j], 0, 0, 0);
          acc1[j] = __builtin_amdgcn_mfma_f32_16x16x32_bf16(av1, bv4, acc1[j], 0, 0, 0);
          acc2[j] = __builtin_amdgcn_mfma_f32_16x16x32_bf16(av2, bv5, acc2[j], 0, 0, 0);
        }
      }
      #pragma unroll
      for (int j = 0; j < 4; ++j) {
        int col = (w * 4 + j) * 16 + ln16;
        int r0 = q * 4;
        Tp[(r0 + 0) * TS + col] = f2bf(acc0[j][0]);
        Tp[(r0 + 1) * TS + col] = f2bf(acc0[j][1]);
        Tp[(r0 + 2) * TS + col] = f2bf(acc0[j][2]);
        Tp[(r0 + 3) * TS + col] = f2bf(acc0[j][3]);
        Tp[(16 + r0 + 0) * TS + col] = f2bf(acc1[j][0]);
        Tp[(16 + r0 + 1) * TS + col] = f2bf(acc1[j][1]);
        Tp[(16 + r0 + 2) * TS + col] = f2bf(acc1[j][2]);
        Tp[(16 + r0 + 3) * TS + col] = f2bf(acc1[j][3]);
        if (q == 0) {
          buf1[0][col] = acc2[j][0];   // v_s0
          buf1[1][col] = acc2[j][1];   // v_s1
        }
      }
    }
    __syncthreads();

    // ================= VALU3: jac/Bq1 (shuffle-reduced) + stage SYRK-W rows =================
    {
      const float* wt = W1 + rg * Hh + kc;
      const float* wb = W1 + (Nn + rg) * Hh + kc;
      float ja0 = 0.f, ja1 = 0.f, bq0 = 0.f, bq1 = 0.f;
      #pragma unroll
      for (int k2 = 0; k2 < 32; k2 += 4) {
        int kk = kc + k2;
        float4 wtv = *(const float4*)&wt[k2];
        float4 wbv = *(const float4*)&wb[k2];
        float4 vA = *(const float4*)&buf1[0][kk];
        float4 vB = *(const float4*)&buf1[1][kk];
        float4 aA = *(const float4*)&act1[0][kk];
        float4 aB = *(const float4*)&act1[1][kk];
        float4 dA = *(const float4*)&d2a[0][kk];
        float4 dB = *(const float4*)&d2a[1][kk];
        float4 rA = *(const float4*)&rbuf[0][kk];
        float4 rB = *(const float4*)&rbuf[1][kk];
        ja0 = fmaf(wtv.x, aA.x * vA.x, ja0); ja0 = fmaf(wtv.y, aA.y * vA.y, ja0);
        ja0 = fmaf(wtv.z, aA.z * vA.z, ja0); ja0 = fmaf(wtv.w, aA.w * vA.w, ja0);
        ja1 = fmaf(wtv.x, aB.x * vB.x, ja1); ja1 = fmaf(wtv.y, aB.y * vB.y, ja1);
        ja1 = fmaf(wtv.z, aB.z * vB.z, ja1); ja1 = fmaf(wtv.w, aB.w * vB.w, ja1);
        bq0 = fmaf(wbv.x, dA.x * vA.x * rA.x, bq0); bq0 = fmaf(wbv.y, dA.y * vA.y * rA.y, bq0);
        bq0 = fmaf(wbv.z, dA.z * vA.z * rA.z, bq0); bq0 = fmaf(wbv.w, dA.w * vA.w * rA.w, bq0);
        bq1 = fmaf(wbv.x, dB.x * vB.x * rB.x, bq1); bq1 = fmaf(wbv.y, dB.y * vB.y * rB.y, bq1);
        bq1 = fmaf(wbv.z, dB.z * vB.z * rB.z, bq1); bq1 = fmaf(wbv.w, dB.w * vB.w * rB.w, bq1);
      }
      ja0 += __shfl_xor(ja0, 1, 64); ja0 += __shfl_xor(ja0, 2, 64); ja0 += __shfl_xor(ja0, 4, 64);
      ja1 += __shfl_xor(ja1, 1, 64); ja1 += __shfl_xor(ja1, 2, 64); ja1 += __shfl_xor(ja1, 4, 64);
      bq0 += __shfl_xor(bq0, 1, 64); bq0 += __shfl_xor(bq0, 2, 64); bq0 += __shfl_xor(bq0, 4, 64);
      bq1 += __shfl_xor(bq1, 1, 64); bq1 += __shfl_xor(bq1, 2, 64); bq1 += __shfl_xor(bq1, 4, 64);
      if ((lane & 7) == 0) {
        jacv[0][rg] += ja0; jacv[1][rg] += ja1;
        Bqv[0][rg] += bq0;  Bqv[1][rg] += bq1;
      }
    }
    {
      // stage wsc rows 0-63: megaA[sm*32+m][k] = d2a[sm][k]*v[sm][k]*W1bot[m][k]
      int m2 = t >> 2, smc = m2 >> 5, m = m2 & 31;
      int kbp = (t & 3) * 2;
      #pragma unroll
      for (int kbi = 0; kbi < 2; ++kbi) {
        int kb = kbp + kbi;
        int base = ((m >> 4) * 8 + kb) * 512 + (m & 15) * 8;
        #pragma unroll
        for (int q2 = 0; q2 < 4; ++q2) {
          bf8_t w8 = *(const bf8_t*)&w1f[base + q2 * 128];
          f4_t lo, hi; bf8_to_f(w8, lo, hi);
          int k0 = kb * 32 + q2 * 8;
          f4_t dv0 = *(const f4_t*)&d2a[smc][k0];
          f4_t dv1 = *(const f4_t*)&d2a[smc][k0 + 4];
          f4_t vv0 = *(const f4_t*)&buf1[smc][k0];
          f4_t vv1 = *(const f4_t*)&buf1[smc][k0 + 4];
          *(bf8_t*)&megaA[m2 * MS + k0] = pack8(lo * (dv0 * vv0), hi * (dv1 * vv1));
        }
      }
    }
    __syncthreads();

    // ================= SYRK phase: SYRK-W (both) + SYRK-T(s1) + Bq2(s1) =================
    for (int kb = 0; kb < 8; ++kb) {
      int kk = kb * 32 + q * 8;
      bf8_t bfr = *(const bf8_t*)&w1f[(ntS * 8 + kb) * 512 + lane * 8];
      bf8_t a0 = *(const bf8_t*)&megaA[(mtS * 16 + ln16) * MS + kk];
      bf8_t a1 = *(const bf8_t*)&megaA[(32 + mtS * 16 + ln16) * MS + kk];
      sacc[0] = __builtin_amdgcn_mfma_f32_16x16x32_bf16(a0, bfr, sacc[0], 0, 0, 0);
      sacc[1] = __builtin_amdgcn_mfma_f32_16x16x32_bf16(a1, bfr, sacc[1], 0, 0, 0);
    }
    for (int jb = 0; jb < 8; ++jb) {
      int jbase = jb * 32 + q * 8;
      f4_t bc0 = *(const f4_t*)&bco[1][jbase];
      f4_t bc1 = *(const f4_t*)&bco[1][jbase + 4];
      bf8_t ta = *(const bf8_t*)&Tp[(mtS * 16 + ln16) * TS + jbase];
      bf8_t tb = *(const bf8_t*)&Tp[(ntS * 16 + ln16) * TS + jbase];
      f4_t lo, hi; bf8_to_f(ta, lo, hi);
      bf8_t afr = pack8(lo * bc0, hi * bc1);
      sacc[1] = __builtin_amdgcn_mfma_f32_16x16x32_bf16(afr, tb, sacc[1], 0, 0, 0);
    }
    {
      float a = 0.f;
      #pragma unroll
      for (int j4 = 0; j4 < 4; ++j4) {
        int jb = kc + j4 * 8;
        bf8_t t8 = *(const bf8_t*)&Tp[rg * TS + jb];
        f4_t lo, hi; bf8_to_f(t8, lo, hi);
        float4 tv0 = *(const float4*)&buf2[1][jb];
        float4 tv1 = *(const float4*)&buf2[1][jb + 4];
        a = fmaf(lo.x, tv0.x, a); a = fmaf(lo.y, tv0.y, a);
        a = fmaf(lo.z, tv0.z, a); a = fmaf(lo.w, tv0.w, a);
        a = fmaf(hi.x, tv1.x, a); a = fmaf(hi.y, tv1.y, a);
        a = fmaf(hi.z, tv1.z, a); a = fmaf(hi.w, tv1.w, a);
      }
      a += __shfl_xor(a, 1, 64);
      a += __shfl_xor(a, 2, 64);
      a += __shfl_xor(a, 4, 64);
      if ((lane & 7) == 0) Bqv[1][rg] += a;
    }
    __syncthreads();
  }

  // ---- Aug assembly (alias region now free) ----
  {
    int col = ntS * 16 + ln16;
    int rowb = mtS * 16 + q * 4;
    #pragma unroll
    for (int sm = 0; sm < 2; ++sm) {
      AugF[(sm * Nn + rowb + 0) * AS + col] = sacc[sm][0];
      AugF[(sm * Nn + rowb + 1) * AS + col] = sacc[sm][1];
      AugF[(sm * Nn + rowb + 2) * AS + col] = sacc[sm][2];
      AugF[(sm * Nn + rowb + 3) * AS + col] = sacc[sm][3];
    }
  }
  __syncthreads();
  if (t < 64) {
    int smp = t >> 5, r = t & 31;
    AugF[(smp * Nn + r) * AS + r] += 2.0f;
    AugF[(smp * Nn + r) * AS + Nn] = jacv[smp][r] - Bqv[smp][r];
  }
  __syncthreads();

  // ---- register Gauss-Jordan, no pivot (A = 2I + small): wave0->s0, wave1->s1 ----
  if (w < 2 && lane < 32) {
    int smp = w, r = lane;
    float a[Nn + 1];
    #pragma unroll
    for (int c = 0; c <= Nn; ++c) a[c] = AugF[(smp * Nn + r) * AS + c];
    float mydiag = 1.f;
    #pragma unroll
    for (int st = 0; st < Nn; ++st) {
      float pd = __shfl(a[st], st, 64);
      mydiag = (r == st) ? pd : mydiag;
      float f = a[st] / pd;
      bool self = (r == st);
      #pragma unroll
      for (int c = st + 1; c <= Nn; ++c) {
        float pc = __shfl(a[c], st, 64);
        if (!self) a[c] = fmaf(-f, pc, a[c]);
      }
    }
    out[(s0 + smp) * Dd + r] = xr[smp][Nn + r];          // qdot
    out[(s0 + smp) * Dd + Nn + r] = a[Nn] / mydiag;      // qdd
  }
}

extern "C" void kernel_launch(void* const* d_in, const int* in_sizes, int n_in,
                              void* d_out, int out_size, void* d_ws, size_t ws_size,
                              hipStream_t stream) {
  const float* x   = (const float*)d_in[0];
  const float* mW1 = (const float*)d_in[1];
  const float* mb1 = (const float*)d_in[2];
  const float* mW2 = (const float*)d_in[3];
  const float* mb2 = (const float*)d_in[4];
  const float* mW3 = (const float*)d_in[5];
  const float* qW1 = (const float*)d_in[6];
  const float* qb1 = (const float*)d_in[7];
  const float* qW2 = (const float*)d_in[8];
  const float* qb2 = (const float*)d_in[9];
  const float* qW3 = (const float*)d_in[10];

  short* ws4 = (short*)d_ws;                          // 2 x 65536 bf16 = 256 KB
  short* ws5 = (short*)((char*)d_ws + 262144);        // 2 x 65536 bf16 = 256 KB
  short* ws1 = (short*)((char*)d_ws + 524288);        // 2 x 8192 bf16  = 32 KB
  short* ws6 = (short*)((char*)d_ws + 557056);        // 2 x 16384 bf16 = 64 KB

  pack_kernel<<<dim3(1216), dim3(256), 0, stream>>>(mW1, mW2, qW1, qW2, ws4, ws5, ws1, ws6);

  const int B = in_sizes[0] / Dd;   // 4096
  lnn_kernel<<<dim3(B / 2), dim3(256), 0, stream>>>(
      x, mW1, mb1, mW2, mb2, mW3, qW1, qb1, qW2, qb2, qW3, ws4, ws5, ws1, ws6, (float*)d_out);
}